// Round 4
// baseline (1773.539 us; speedup 1.0000x reference)
//
#include <hip/hip_runtime.h>
#include <hip/hip_bf16.h>
#include <stdint.h>

// Problem constants (from reference)
#define N_SAM 10000
#define N_GEN 20000
#define DSAM  2000
#define DGEN  500
#define DIM0  256

typedef __hip_bfloat16 bf16;

__device__ __forceinline__ float bfbits2f(unsigned short u) {
    unsigned v = ((unsigned)u) << 16;
    return __builtin_bit_cast(float, v);
}
__device__ __forceinline__ unsigned short f2bfbits(float f) {
    bf16 h = __float2bfloat16(f);
    return __builtin_bit_cast(unsigned short, h);
}

// ---------------------------------------------------------------------------
// Degree histograms (4 at once)
// ---------------------------------------------------------------------------
__global__ __launch_bounds__(256) void hist4_kernel(
    const int* __restrict__ ssg, const int* __restrict__ dsg,
    const int* __restrict__ sgs, const int* __restrict__ dgs,
    unsigned* __restrict__ c_ssg, unsigned* __restrict__ c_dsg,
    unsigned* __restrict__ c_sgs, unsigned* __restrict__ c_dgs, int ne) {
    int i = blockIdx.x * blockDim.x + threadIdx.x;
    if (i < ne) {
        atomicAdd(&c_ssg[ssg[i]], 1u);
        atomicAdd(&c_dsg[dsg[i]], 1u);
        atomicAdd(&c_sgs[sgs[i]], 1u);
        atomicAdd(&c_dgs[dgs[i]], 1u);
    }
}

// ---------------------------------------------------------------------------
// Exclusive scan (single block, chunked Hillis-Steele). row[n] = total.
// ---------------------------------------------------------------------------
__global__ __launch_bounds__(1024) void scan_kernel(
    const unsigned* __restrict__ cnt, unsigned* __restrict__ row,
    unsigned* __restrict__ cur, int n) {
    __shared__ unsigned sdata[1024];
    __shared__ unsigned carry_s;
    int t = threadIdx.x;
    if (t == 0) carry_s = 0;
    __syncthreads();
    for (int base = 0; base < n; base += 1024) {
        int i = base + t;
        unsigned v = (i < n) ? cnt[i] : 0u;
        sdata[t] = v;
        __syncthreads();
        for (int off = 1; off < 1024; off <<= 1) {
            unsigned add = (t >= off) ? sdata[t - off] : 0u;
            __syncthreads();
            sdata[t] += add;
            __syncthreads();
        }
        unsigned incl = sdata[t];
        unsigned carry = carry_s;
        if (i < n) {
            unsigned ex = carry + incl - v;
            row[i] = ex;
            cur[i] = ex;
        }
        __syncthreads();
        if (t == 1023) carry_s = carry + incl;
        __syncthreads();
    }
    if (t == 0) row[n] = carry_s;
}

// ---------------------------------------------------------------------------
// Degree normalizers: rsqrt(max(deg,1))
// ---------------------------------------------------------------------------
__global__ __launch_bounds__(256) void degnorm_kernel(
    const unsigned* __restrict__ c_ssg, const unsigned* __restrict__ c_dsg,
    const unsigned* __restrict__ c_sgs, const unsigned* __restrict__ c_dgs,
    float* __restrict__ rs_out_sam, float* __restrict__ rs_in_gen,
    float* __restrict__ rs_out_gen, float* __restrict__ rs_in_sam) {
    int i = blockIdx.x * blockDim.x + threadIdx.x;
    if (i < N_SAM) {
        unsigned a = c_ssg[i]; if (a < 1u) a = 1u;
        unsigned b = c_dgs[i]; if (b < 1u) b = 1u;
        rs_out_sam[i] = rsqrtf((float)a);
        rs_in_sam[i]  = rsqrtf((float)b);
    }
    if (i < N_GEN) {
        unsigned a = c_dsg[i]; if (a < 1u) a = 1u;
        unsigned b = c_sgs[i]; if (b < 1u) b = 1u;
        rs_in_gen[i]  = rsqrtf((float)a);
        rs_out_gen[i] = rsqrtf((float)b);
    }
}

// ---------------------------------------------------------------------------
// CSR scatter (dst-sorted edge list; col = src)
// ---------------------------------------------------------------------------
__global__ __launch_bounds__(256) void scatter_kernel(
    const int* __restrict__ src, const int* __restrict__ dst,
    unsigned* __restrict__ cur, int* __restrict__ col, int ne) {
    int i = blockIdx.x * blockDim.x + threadIdx.x;
    if (i < ne) {
        unsigned p = atomicAdd(&cur[dst[i]], 1u);
        col[p] = src[i];
    }
}

// ---------------------------------------------------------------------------
// Split-K tiled GEMM: C[M,N] += rowscale(A)[M,K_slab] * B[K_slab,N] (+bias on z==0)
// fp32 atomic accumulate into pre-zeroed C. BM=BN=64, BK=16, 256 thr, 4x4/thr.
// Kslab must be a multiple of 16 (slab starts stay 16-aligned for float4 loads).
// ---------------------------------------------------------------------------
__global__ __launch_bounds__(256) void gemm_splitk(
    const float* __restrict__ A, const float* __restrict__ B,
    const float* __restrict__ rowscale, const float* __restrict__ bias,
    float* __restrict__ C, int M, int N, int K, int Kslab) {
    const int BM = 64, BN = 64, BK = 16;
    __shared__ float As[BK][BM];
    __shared__ float Bs[BK][BN];
    int t  = threadIdx.x;
    int m0 = blockIdx.y * BM, n0 = blockIdx.x * BN;
    int kb = blockIdx.z * Kslab;
    int ke = kb + Kslab; if (ke > K) ke = K;
    int tx = t & 15, ty = t >> 4;
    int ar = t >> 2;        // A row within tile
    int ak = (t & 3) * 4;   // A k offset within tile
    int bk = t >> 4;        // B k row within tile
    int bn = (t & 15) * 4;  // B col offset within tile

    float acc[4][4] = {};

    for (int k0 = kb; k0 < ke; k0 += BK) {
        int gm = m0 + ar;
        float scale = 1.0f;
        if (rowscale != nullptr && gm < M) scale = rowscale[gm];
        int gk0 = k0 + ak;
        if (gm < M && gk0 + 3 < ke) {
            float4 u = *reinterpret_cast<const float4*>(A + (size_t)gm * K + gk0);
            As[ak + 0][ar] = u.x * scale;
            As[ak + 1][ar] = u.y * scale;
            As[ak + 2][ar] = u.z * scale;
            As[ak + 3][ar] = u.w * scale;
        } else {
            #pragma unroll
            for (int j = 0; j < 4; j++) {
                int gk = gk0 + j;
                float v = 0.f;
                if (gm < M && gk < ke) v = A[(size_t)gm * K + gk];
                As[ak + j][ar] = v * scale;
            }
        }
        {
            int gk = k0 + bk;
            if (gk < ke) {
                float4 u = *reinterpret_cast<const float4*>(B + (size_t)gk * N + n0 + bn);
                Bs[bk][bn + 0] = u.x;
                Bs[bk][bn + 1] = u.y;
                Bs[bk][bn + 2] = u.z;
                Bs[bk][bn + 3] = u.w;
            } else {
                Bs[bk][bn + 0] = 0.f; Bs[bk][bn + 1] = 0.f;
                Bs[bk][bn + 2] = 0.f; Bs[bk][bn + 3] = 0.f;
            }
        }
        __syncthreads();
        #pragma unroll
        for (int kk = 0; kk < BK; kk++) {
            float4 a = *reinterpret_cast<const float4*>(&As[kk][ty * 4]);
            float4 b = *reinterpret_cast<const float4*>(&Bs[kk][tx * 4]);
            float av[4] = {a.x, a.y, a.z, a.w};
            float bv[4] = {b.x, b.y, b.z, b.w};
            #pragma unroll
            for (int i = 0; i < 4; i++)
                #pragma unroll
                for (int j = 0; j < 4; j++)
                    acc[i][j] += av[i] * bv[j];
        }
        __syncthreads();
    }
    bool addb = (bias != nullptr) && (blockIdx.z == 0);
    #pragma unroll
    for (int i = 0; i < 4; i++) {
        int gm = m0 + ty * 4 + i;
        if (gm >= M) continue;
        #pragma unroll
        for (int j = 0; j < 4; j++) {
            int gn = n0 + tx * 4 + j;
            float v = acc[i][j];
            if (addb) v += bias[gn];
            unsafeAtomicAdd(&C[(size_t)gm * N + gn], v);
        }
    }
}

// ---------------------------------------------------------------------------
// fp32 -> packed bf16 convert (4 elems/thread)
// ---------------------------------------------------------------------------
__global__ __launch_bounds__(256) void f32_to_bf16_kernel(
    const float* __restrict__ in, unsigned short* __restrict__ out, int n4) {
    int i = blockIdx.x * blockDim.x + threadIdx.x;
    if (i < n4) {
        float4 v = reinterpret_cast<const float4*>(in)[i];
        ushort4 o;
        o.x = f2bfbits(v.x); o.y = f2bfbits(v.y);
        o.z = f2bfbits(v.z); o.w = f2bfbits(v.w);
        reinterpret_cast<ushort4*>(out)[i] = o;
    }
}

// ---------------------------------------------------------------------------
// CSR aggregation over bf16 P:
// out[r,:] = leaky( rs_in[r] * sum_{e in row r} P[col[e],:] + bias )
// One wave per dst row; lane handles VPL contiguous columns (D = 64*VPL).
// ---------------------------------------------------------------------------
template <int VPL>
__device__ __forceinline__ void load_bf16_row(const unsigned short* p, float* v);
template <>
__device__ __forceinline__ void load_bf16_row<4>(const unsigned short* p, float* v) {
    ushort4 u = *reinterpret_cast<const ushort4*>(p);
    v[0] = bfbits2f(u.x); v[1] = bfbits2f(u.y);
    v[2] = bfbits2f(u.z); v[3] = bfbits2f(u.w);
}
template <>
__device__ __forceinline__ void load_bf16_row<2>(const unsigned short* p, float* v) {
    ushort2 u = *reinterpret_cast<const ushort2*>(p);
    v[0] = bfbits2f(u.x); v[1] = bfbits2f(u.y);
}
template <>
__device__ __forceinline__ void load_bf16_row<1>(const unsigned short* p, float* v) {
    v[0] = bfbits2f(*p);
}

template <int VPL>
__global__ __launch_bounds__(256) void agg_csr_kernel(
    const unsigned* __restrict__ rowptr, const int* __restrict__ col,
    const unsigned short* __restrict__ P, const float* __restrict__ rs_in,
    const float* __restrict__ bias,
    float* __restrict__ outF, int n_dst) {
    const int D = VPL * 64;
    int wave = threadIdx.x >> 6;
    int lane = threadIdx.x & 63;
    int r = blockIdx.x * 4 + wave;
    if (r >= n_dst) return;

    unsigned e0 = rowptr[r], e1 = rowptr[r + 1];
    float acc[VPL] = {};
    float acc2[VPL] = {};
    float t0[VPL], t1[VPL];
    unsigned e = e0;
    for (; e + 2 <= e1; e += 2) {
        int s0 = col[e];
        int s1 = col[e + 1];
        load_bf16_row<VPL>(P + (size_t)s0 * D + lane * VPL, t0);
        load_bf16_row<VPL>(P + (size_t)s1 * D + lane * VPL, t1);
        #pragma unroll
        for (int j = 0; j < VPL; j++) { acc[j] += t0[j]; acc2[j] += t1[j]; }
    }
    if (e < e1) {
        int s0 = col[e];
        load_bf16_row<VPL>(P + (size_t)s0 * D + lane * VPL, t0);
        #pragma unroll
        for (int j = 0; j < VPL; j++) acc[j] += t0[j];
    }
    float rs = rs_in[r];
    #pragma unroll
    for (int j = 0; j < VPL; j++) {
        int c = lane * VPL + j;
        float v = (acc[j] + acc2[j]) * rs + bias[c];
        v = (v >= 0.f) ? v : 0.25f * v;
        outF[(size_t)r * D + c] = v;
    }
}

// ---------------------------------------------------------------------------
// Launch
// ---------------------------------------------------------------------------
extern "C" void kernel_launch(void* const* d_in, const int* in_sizes, int n_in,
                              void* d_out, int out_size, void* d_ws, size_t ws_size,
                              hipStream_t stream) {
    const float* sam_feat = (const float*)d_in[0];
    const float* gen_feat = (const float*)d_in[1];
    const int* src_sg = (const int*)d_in[2];
    const int* dst_sg = (const int*)d_in[3];
    const int* src_gs = (const int*)d_in[4];
    const int* dst_gs = (const int*)d_in[5];
    const float* l1W = (const float*)d_in[6];
    const float* l1b = (const float*)d_in[7];
    const float* l2W = (const float*)d_in[8];
    const float* l2b = (const float*)d_in[9];
    const float* Wsg[3] = {(const float*)d_in[10], (const float*)d_in[14], (const float*)d_in[18]};
    const float* bsg[3] = {(const float*)d_in[11], (const float*)d_in[15], (const float*)d_in[19]};
    const float* Wgs[3] = {(const float*)d_in[12], (const float*)d_in[16], (const float*)d_in[20]};
    const float* bgs[3] = {(const float*)d_in[13], (const float*)d_in[17], (const float*)d_in[21]};
    const int NE = in_sizes[2];

    // ---- workspace carve ----
    char* base = (char*)d_ws;
    size_t off = 0;
    auto alloc = [&](size_t bytes) -> char* {
        char* p = base + off;
        off = (off + bytes + 255) & ~(size_t)255;
        return p;
    };
    unsigned* cnt_ssg = (unsigned*)alloc(N_SAM * 4);
    unsigned* cnt_dsg = (unsigned*)alloc(N_GEN * 4);
    unsigned* cnt_sgs = (unsigned*)alloc(N_GEN * 4);
    unsigned* cnt_dgs = (unsigned*)alloc(N_SAM * 4);
    size_t cnt_bytes = off;  // contiguous zero region (counts)
    unsigned* row_sg = (unsigned*)alloc((N_GEN + 1) * 4);
    unsigned* row_gs = (unsigned*)alloc((N_SAM + 1) * 4);
    unsigned* cur_sg = (unsigned*)alloc(N_GEN * 4);
    unsigned* cur_gs = (unsigned*)alloc(N_SAM * 4);
    float* rs_out_sam = (float*)alloc(N_SAM * 4);
    float* rs_in_sam  = (float*)alloc(N_SAM * 4);
    float* rs_out_gen = (float*)alloc(N_GEN * 4);
    float* rs_in_gen  = (float*)alloc(N_GEN * 4);
    int* col_sg = (int*)alloc((size_t)NE * 4);
    int* col_gs = (int*)alloc((size_t)NE * 4);
    // GEMM accumulation region (contiguous for one big initial memset)
    char* zero_base = base + off;
    float* hs  = (float*)alloc((size_t)N_SAM * 256 * 4);
    float* hg  = (float*)alloc((size_t)N_GEN * 256 * 4);
    float* psf = (float*)alloc((size_t)N_SAM * 256 * 4);
    float* pgf = (float*)alloc((size_t)N_GEN * 256 * 4);
    size_t zero_bytes = (base + off) - zero_base;
    // bf16 gather buffers
    unsigned short* ps = (unsigned short*)alloc((size_t)N_SAM * 256 * 2);
    unsigned short* pg = (unsigned short*)alloc((size_t)N_GEN * 256 * 2);
    (void)ws_size;

    // ---- graph preprocessing ----
    hipMemsetAsync(base, 0, cnt_bytes, stream);
    hipMemsetAsync(zero_base, 0, zero_bytes, stream);
    int neb = (NE + 255) / 256;
    hist4_kernel<<<neb, 256, 0, stream>>>(src_sg, dst_sg, src_gs, dst_gs,
                                          cnt_ssg, cnt_dsg, cnt_sgs, cnt_dgs, NE);
    scan_kernel<<<1, 1024, 0, stream>>>(cnt_dsg, row_sg, cur_sg, N_GEN);
    scan_kernel<<<1, 1024, 0, stream>>>(cnt_dgs, row_gs, cur_gs, N_SAM);
    degnorm_kernel<<<(N_GEN + 255) / 256, 256, 0, stream>>>(
        cnt_ssg, cnt_dsg, cnt_sgs, cnt_dgs,
        rs_out_sam, rs_in_gen, rs_out_gen, rs_in_sam);
    scatter_kernel<<<neb, 256, 0, stream>>>(src_sg, dst_sg, cur_sg, col_sg, NE);
    scatter_kernel<<<neb, 256, 0, stream>>>(src_gs, dst_gs, cur_gs, col_gs, NE);

    dim3 blk(256);
    const int GY_SAM = (N_SAM + 63) / 64;  // 157
    const int GY_GEN = (N_GEN + 63) / 64;  // 313

    // ---- input projections (split-K for occupancy) ----
    gemm_splitk<<<dim3(4, GY_SAM, 4), blk, 0, stream>>>(
        sam_feat, l1W, nullptr, l1b, hs, N_SAM, 256, DSAM, 512);
    gemm_splitk<<<dim3(4, GY_GEN, 2), blk, 0, stream>>>(
        gen_feat, l2W, nullptr, l2b, hg, N_GEN, 256, DGEN, 256);

    // ---- layer 1: 256 -> 256 ----
    gemm_splitk<<<dim3(4, GY_SAM, 2), blk, 0, stream>>>(hs, Wsg[0], rs_out_sam, nullptr, psf, N_SAM, 256, 256, 128);
    gemm_splitk<<<dim3(4, GY_GEN, 2), blk, 0, stream>>>(hg, Wgs[0], rs_out_gen, nullptr, pgf, N_GEN, 256, 256, 128);
    f32_to_bf16_kernel<<<(N_SAM * 256 / 4 + 255) / 256, blk, 0, stream>>>(psf, ps, N_SAM * 256 / 4);
    f32_to_bf16_kernel<<<(N_GEN * 256 / 4 + 255) / 256, blk, 0, stream>>>(pgf, pg, N_GEN * 256 / 4);
    agg_csr_kernel<4><<<(N_GEN + 3) / 4, blk, 0, stream>>>(row_sg, col_sg, ps, rs_in_gen, bsg[0], hg, N_GEN);
    agg_csr_kernel<4><<<(N_SAM + 3) / 4, blk, 0, stream>>>(row_gs, col_gs, pg, rs_in_sam, bgs[0], hs, N_SAM);

    // ---- layer 2: 256 -> 128 ----
    hipMemsetAsync(psf, 0, (size_t)N_SAM * 128 * 4, stream);
    hipMemsetAsync(pgf, 0, (size_t)N_GEN * 128 * 4, stream);
    gemm_splitk<<<dim3(2, GY_SAM, 4), blk, 0, stream>>>(hs, Wsg[1], rs_out_sam, nullptr, psf, N_SAM, 128, 256, 64);
    gemm_splitk<<<dim3(2, GY_GEN, 2), blk, 0, stream>>>(hg, Wgs[1], rs_out_gen, nullptr, pgf, N_GEN, 128, 256, 128);
    f32_to_bf16_kernel<<<(N_SAM * 128 / 4 + 255) / 256, blk, 0, stream>>>(psf, ps, N_SAM * 128 / 4);
    f32_to_bf16_kernel<<<(N_GEN * 128 / 4 + 255) / 256, blk, 0, stream>>>(pgf, pg, N_GEN * 128 / 4);
    agg_csr_kernel<2><<<(N_GEN + 3) / 4, blk, 0, stream>>>(row_sg, col_sg, ps, rs_in_gen, bsg[1], hg, N_GEN);
    agg_csr_kernel<2><<<(N_SAM + 3) / 4, blk, 0, stream>>>(row_gs, col_gs, pg, rs_in_sam, bgs[1], hs, N_SAM);

    // ---- layer 3: 128 -> 64, fp32 outputs straight into d_out ----
    hipMemsetAsync(psf, 0, (size_t)N_SAM * 64 * 4, stream);
    hipMemsetAsync(pgf, 0, (size_t)N_GEN * 64 * 4, stream);
    gemm_splitk<<<dim3(1, GY_SAM, 8), blk, 0, stream>>>(hs, Wsg[2], rs_out_sam, nullptr, psf, N_SAM, 64, 128, 16);
    gemm_splitk<<<dim3(1, GY_GEN, 4), blk, 0, stream>>>(hg, Wgs[2], rs_out_gen, nullptr, pgf, N_GEN, 64, 128, 32);
    f32_to_bf16_kernel<<<(N_SAM * 64 / 4 + 255) / 256, blk, 0, stream>>>(psf, ps, N_SAM * 64 / 4);
    f32_to_bf16_kernel<<<(N_GEN * 64 / 4 + 255) / 256, blk, 0, stream>>>(pgf, pg, N_GEN * 64 / 4);
    float* out_sam = (float*)d_out;
    float* out_gen = out_sam + (size_t)N_SAM * 64;
    agg_csr_kernel<1><<<(N_GEN + 3) / 4, blk, 0, stream>>>(row_sg, col_sg, ps, rs_in_gen, bsg[2], out_gen, N_GEN);
    agg_csr_kernel<1><<<(N_SAM + 3) / 4, blk, 0, stream>>>(row_gs, col_gs, pg, rs_in_sam, bgs[2], out_sam, N_SAM);
}

// Round 5
// 1049.777 us; speedup vs baseline: 1.6894x; 1.6894x over previous
//
#include <hip/hip_runtime.h>
#include <hip/hip_bf16.h>
#include <stdint.h>

#define N_SAM 10000
#define N_GEN 20000
#define DSAM  2000
#define DGEN  500

typedef __hip_bfloat16 bf16;
typedef short bf16x8 __attribute__((ext_vector_type(8)));
typedef float f32x4 __attribute__((ext_vector_type(4)));

__device__ __forceinline__ float bfbits2f(unsigned short u) {
    unsigned v = ((unsigned)u) << 16;
    return __builtin_bit_cast(float, v);
}
__device__ __forceinline__ unsigned short f2bfbits(float f) {
    bf16 h = __float2bfloat16(f);
    return __builtin_bit_cast(unsigned short, h);
}

// ---------------------------------------------------------------------------
// Degree histograms (4 at once)
// ---------------------------------------------------------------------------
__global__ __launch_bounds__(256) void hist4_kernel(
    const int* __restrict__ ssg, const int* __restrict__ dsg,
    const int* __restrict__ sgs, const int* __restrict__ dgs,
    unsigned* __restrict__ c_ssg, unsigned* __restrict__ c_dsg,
    unsigned* __restrict__ c_sgs, unsigned* __restrict__ c_dgs, int ne) {
    int i = blockIdx.x * blockDim.x + threadIdx.x;
    if (i < ne) {
        atomicAdd(&c_ssg[ssg[i]], 1u);
        atomicAdd(&c_dsg[dsg[i]], 1u);
        atomicAdd(&c_sgs[sgs[i]], 1u);
        atomicAdd(&c_dgs[dgs[i]], 1u);
    }
}

// ---------------------------------------------------------------------------
// Two exclusive scans in one launch (block 0 / block 1). row[n] = total.
// ---------------------------------------------------------------------------
__global__ __launch_bounds__(1024) void scan2_kernel(
    const unsigned* __restrict__ c0, unsigned* __restrict__ r0, unsigned* __restrict__ u0, int nA,
    const unsigned* __restrict__ c1, unsigned* __restrict__ r1, unsigned* __restrict__ u1, int nB) {
    const unsigned* cnt; unsigned *row, *cur; int n;
    if (blockIdx.x == 0) { cnt = c0; row = r0; cur = u0; n = nA; }
    else                 { cnt = c1; row = r1; cur = u1; n = nB; }
    __shared__ unsigned sdata[1024];
    __shared__ unsigned carry_s;
    int t = threadIdx.x;
    if (t == 0) carry_s = 0;
    __syncthreads();
    for (int base = 0; base < n; base += 1024) {
        int i = base + t;
        unsigned v = (i < n) ? cnt[i] : 0u;
        sdata[t] = v;
        __syncthreads();
        for (int off = 1; off < 1024; off <<= 1) {
            unsigned add = (t >= off) ? sdata[t - off] : 0u;
            __syncthreads();
            sdata[t] += add;
            __syncthreads();
        }
        unsigned incl = sdata[t];
        unsigned carry = carry_s;
        if (i < n) {
            unsigned ex = carry + incl - v;
            row[i] = ex;
            cur[i] = ex;
        }
        __syncthreads();
        if (t == 1023) carry_s = carry + incl;
        __syncthreads();
    }
    if (t == 0) row[n] = carry_s;
}

// ---------------------------------------------------------------------------
// Degree normalizers: rsqrt(max(deg,1))
// ---------------------------------------------------------------------------
__global__ __launch_bounds__(256) void degnorm_kernel(
    const unsigned* __restrict__ c_ssg, const unsigned* __restrict__ c_dsg,
    const unsigned* __restrict__ c_sgs, const unsigned* __restrict__ c_dgs,
    float* __restrict__ rs_out_sam, float* __restrict__ rs_in_gen,
    float* __restrict__ rs_out_gen, float* __restrict__ rs_in_sam) {
    int i = blockIdx.x * blockDim.x + threadIdx.x;
    if (i < N_SAM) {
        unsigned a = c_ssg[i]; if (a < 1u) a = 1u;
        unsigned b = c_dgs[i]; if (b < 1u) b = 1u;
        rs_out_sam[i] = rsqrtf((float)a);
        rs_in_sam[i]  = rsqrtf((float)b);
    }
    if (i < N_GEN) {
        unsigned a = c_dsg[i]; if (a < 1u) a = 1u;
        unsigned b = c_sgs[i]; if (b < 1u) b = 1u;
        rs_in_gen[i]  = rsqrtf((float)a);
        rs_out_gen[i] = rsqrtf((float)b);
    }
}

// ---------------------------------------------------------------------------
// Both CSR scatters in one launch (dst-sorted edge lists; col = src)
// ---------------------------------------------------------------------------
__global__ __launch_bounds__(256) void scatter2_kernel(
    const int* __restrict__ src_sg, const int* __restrict__ dst_sg,
    const int* __restrict__ src_gs, const int* __restrict__ dst_gs,
    unsigned* __restrict__ cur_sg, int* __restrict__ col_sg,
    unsigned* __restrict__ cur_gs, int* __restrict__ col_gs, int ne) {
    int i = blockIdx.x * blockDim.x + threadIdx.x;
    if (i < ne) {
        unsigned p = atomicAdd(&cur_sg[dst_sg[i]], 1u);
        col_sg[p] = src_sg[i];
        unsigned q = atomicAdd(&cur_gs[dst_gs[i]], 1u);
        col_gs[q] = src_gs[i];
    }
}

// ---------------------------------------------------------------------------
// Weight transpose+convert: W[K][N] fp32 -> WT[N][Kp] bf16, zero-pad k in [K,Kp)
// All 8 matrices in one launch via blockIdx.z.
// ---------------------------------------------------------------------------
struct WDesc { const float* src; unsigned short* dst; int K, N, Kp; };
struct WPack { WDesc d[8]; };

__global__ __launch_bounds__(256) void transpose_weights_kernel(WPack p) {
    WDesc d = p.d[blockIdx.z];
    int n  = blockIdx.x * 32 + threadIdx.x;
    int kp = blockIdx.y * 8 + threadIdx.y;
    if (n >= d.N || kp >= d.Kp) return;
    float v = (kp < d.K) ? d.src[(size_t)kp * d.N + n] : 0.0f;
    d.dst[(size_t)n * d.Kp + kp] = f2bfbits(v);
}

// ---------------------------------------------------------------------------
// MFMA bf16 GEMM: C[M][N](bf16) = rowscale(A)[M][K] * BT[N][Kp]^T (+ bias)
// A: fp32 or bf16(ushort) row-major, stride K. BT: bf16 [N][Kp], Kp=ceil32(K),
// zero-padded. 256 thr = 4 waves; block tile 64x64; wave tile 32x32 (2x2
// mfma_f32_16x16x32_bf16); BK=32. LDS rows padded to 40 shorts (80 B).
// N must be a multiple of 64.
// ---------------------------------------------------------------------------
template <typename AT>
__global__ __launch_bounds__(256) void gemm_mfma(
    const AT* __restrict__ A, const unsigned short* __restrict__ BT,
    const float* __restrict__ rowscale, const float* __restrict__ bias,
    unsigned short* __restrict__ C, int M, int N, int K, int Kp) {
    const int BM = 64, BN = 64, BK = 32, BKP = 40;
    __shared__ __attribute__((aligned(16))) unsigned short As[BM][BKP];
    __shared__ __attribute__((aligned(16))) unsigned short Bs[BN][BKP];
    int t = threadIdx.x;
    int m0 = blockIdx.y * BM, n0 = blockIdx.x * BN;
    int wave = t >> 6, lane = t & 63;
    int wm = (wave >> 1) * 32, wn = (wave & 1) * 32;
    int q = lane >> 4, mr = lane & 15;

    // loader: each thread stages 8 k's of one row (A and B symmetric)
    int lr = t >> 2;         // tile row 0..63
    int lk = (t & 3) * 8;    // k offset {0,8,16,24}

    f32x4 acc[2][2] = {};

    int gm = m0 + lr;
    float scale = 1.0f;
    if (rowscale != nullptr && gm < M) scale = rowscale[gm];

    for (int k0 = 0; k0 < Kp; k0 += BK) {
        // ---- stage A tile ----
        {
            int gk = k0 + lk;
            unsigned short tv[8];
            if (gm < M && gk + 8 <= K) {
                if constexpr (sizeof(AT) == 4) {
                    const float* ap = (const float*)A + (size_t)gm * K + gk;
                    float4 u0 = *reinterpret_cast<const float4*>(ap);
                    float4 u1 = *reinterpret_cast<const float4*>(ap + 4);
                    tv[0] = f2bfbits(u0.x * scale); tv[1] = f2bfbits(u0.y * scale);
                    tv[2] = f2bfbits(u0.z * scale); tv[3] = f2bfbits(u0.w * scale);
                    tv[4] = f2bfbits(u1.x * scale); tv[5] = f2bfbits(u1.y * scale);
                    tv[6] = f2bfbits(u1.z * scale); tv[7] = f2bfbits(u1.w * scale);
                } else {
                    const unsigned short* ap = (const unsigned short*)A + (size_t)gm * K + gk;
                    ushort4 u0 = *reinterpret_cast<const ushort4*>(ap);
                    ushort4 u1 = *reinterpret_cast<const ushort4*>(ap + 4);
                    if (rowscale != nullptr) {
                        tv[0] = f2bfbits(bfbits2f(u0.x) * scale);
                        tv[1] = f2bfbits(bfbits2f(u0.y) * scale);
                        tv[2] = f2bfbits(bfbits2f(u0.z) * scale);
                        tv[3] = f2bfbits(bfbits2f(u0.w) * scale);
                        tv[4] = f2bfbits(bfbits2f(u1.x) * scale);
                        tv[5] = f2bfbits(bfbits2f(u1.y) * scale);
                        tv[6] = f2bfbits(bfbits2f(u1.z) * scale);
                        tv[7] = f2bfbits(bfbits2f(u1.w) * scale);
                    } else {
                        tv[0] = u0.x; tv[1] = u0.y; tv[2] = u0.z; tv[3] = u0.w;
                        tv[4] = u1.x; tv[5] = u1.y; tv[6] = u1.z; tv[7] = u1.w;
                    }
                }
            } else {
                #pragma unroll
                for (int j = 0; j < 8; j++) {
                    float v = 0.0f;
                    int k = gk + j;
                    if (gm < M && k < K) {
                        if constexpr (sizeof(AT) == 4) v = ((const float*)A)[(size_t)gm * K + k];
                        else v = bfbits2f(((const unsigned short*)A)[(size_t)gm * K + k]);
                    }
                    tv[j] = f2bfbits(v * scale);
                }
            }
            *reinterpret_cast<ushort4*>(&As[lr][lk])     = make_ushort4(tv[0], tv[1], tv[2], tv[3]);
            *reinterpret_cast<ushort4*>(&As[lr][lk + 4]) = make_ushort4(tv[4], tv[5], tv[6], tv[7]);
        }
        // ---- stage B tile (BT is padded: no k guard; N multiple of 64: no n guard) ----
        {
            const unsigned short* bp = BT + (size_t)(n0 + lr) * Kp + k0 + lk;
            ushort4 u0 = *reinterpret_cast<const ushort4*>(bp);
            ushort4 u1 = *reinterpret_cast<const ushort4*>(bp + 4);
            *reinterpret_cast<ushort4*>(&Bs[lr][lk])     = u0;
            *reinterpret_cast<ushort4*>(&Bs[lr][lk + 4]) = u1;
        }
        __syncthreads();
        // ---- compute: 2x2 mfma 16x16x32 per wave ----
        bf16x8 af[2], bf[2];
        #pragma unroll
        for (int i = 0; i < 2; i++)
            af[i] = *reinterpret_cast<const bf16x8*>(&As[wm + i * 16 + mr][q * 8]);
        #pragma unroll
        for (int j = 0; j < 2; j++)
            bf[j] = *reinterpret_cast<const bf16x8*>(&Bs[wn + j * 16 + mr][q * 8]);
        #pragma unroll
        for (int i = 0; i < 2; i++)
            #pragma unroll
            for (int j = 0; j < 2; j++)
                acc[i][j] = __builtin_amdgcn_mfma_f32_16x16x32_bf16(af[i], bf[j], acc[i][j], 0, 0, 0);
        __syncthreads();
    }
    // ---- epilogue: C/D layout row=(lane>>4)*4+reg, col=lane&15 ----
    #pragma unroll
    for (int i = 0; i < 2; i++) {
        #pragma unroll
        for (int r = 0; r < 4; r++) {
            int row = m0 + wm + i * 16 + q * 4 + r;
            if (row >= M) continue;
            #pragma unroll
            for (int j = 0; j < 2; j++) {
                int col = n0 + wn + j * 16 + mr;
                float v = acc[i][j][r];
                if (bias != nullptr) v += bias[col];
                C[(size_t)row * N + col] = f2bfbits(v);
            }
        }
    }
}

// ---------------------------------------------------------------------------
// CSR aggregation over bf16 P:
// out[r,:] = leaky( rs_in[r] * sum_{e in row r} P[col[e],:] + bias )
// One wave per dst row; lane handles VPL contiguous columns (D = 64*VPL).
// OUTBF: write bf16 (intermediate H) else fp32 (final output).
// ---------------------------------------------------------------------------
template <int VPL>
__device__ __forceinline__ void load_bf16_row(const unsigned short* p, float* v);
template <>
__device__ __forceinline__ void load_bf16_row<4>(const unsigned short* p, float* v) {
    ushort4 u = *reinterpret_cast<const ushort4*>(p);
    v[0] = bfbits2f(u.x); v[1] = bfbits2f(u.y);
    v[2] = bfbits2f(u.z); v[3] = bfbits2f(u.w);
}
template <>
__device__ __forceinline__ void load_bf16_row<2>(const unsigned short* p, float* v) {
    ushort2 u = *reinterpret_cast<const ushort2*>(p);
    v[0] = bfbits2f(u.x); v[1] = bfbits2f(u.y);
}
template <>
__device__ __forceinline__ void load_bf16_row<1>(const unsigned short* p, float* v) {
    v[0] = bfbits2f(*p);
}

template <int VPL, bool OUTBF>
__global__ __launch_bounds__(256) void agg_csr_kernel(
    const unsigned* __restrict__ rowptr, const int* __restrict__ col,
    const unsigned short* __restrict__ P, const float* __restrict__ rs_in,
    const float* __restrict__ bias,
    float* __restrict__ outF, unsigned short* __restrict__ outB, int n_dst) {
    const int D = VPL * 64;
    int wave = threadIdx.x >> 6;
    int lane = threadIdx.x & 63;
    int r = blockIdx.x * 4 + wave;
    if (r >= n_dst) return;

    unsigned e0 = rowptr[r], e1 = rowptr[r + 1];
    float acc[VPL] = {};
    float acc2[VPL] = {};
    float t0[VPL], t1[VPL];
    unsigned e = e0;
    for (; e + 2 <= e1; e += 2) {
        int s0 = col[e];
        int s1 = col[e + 1];
        load_bf16_row<VPL>(P + (size_t)s0 * D + lane * VPL, t0);
        load_bf16_row<VPL>(P + (size_t)s1 * D + lane * VPL, t1);
        #pragma unroll
        for (int j = 0; j < VPL; j++) { acc[j] += t0[j]; acc2[j] += t1[j]; }
    }
    if (e < e1) {
        int s0 = col[e];
        load_bf16_row<VPL>(P + (size_t)s0 * D + lane * VPL, t0);
        #pragma unroll
        for (int j = 0; j < VPL; j++) acc[j] += t0[j];
    }
    float rs = rs_in[r];
    float res[VPL];
    #pragma unroll
    for (int j = 0; j < VPL; j++) {
        float v = (acc[j] + acc2[j]) * rs + bias[lane * VPL + j];
        res[j] = (v >= 0.f) ? v : 0.25f * v;
    }
    if constexpr (OUTBF) {
        unsigned short* op = outB + (size_t)r * D + lane * VPL;
        if constexpr (VPL == 4) {
            *reinterpret_cast<ushort4*>(op) =
                make_ushort4(f2bfbits(res[0]), f2bfbits(res[1]), f2bfbits(res[2]), f2bfbits(res[3]));
        } else if constexpr (VPL == 2) {
            *reinterpret_cast<ushort2*>(op) = make_ushort2(f2bfbits(res[0]), f2bfbits(res[1]));
        } else {
            *op = f2bfbits(res[0]);
        }
    } else {
        #pragma unroll
        for (int j = 0; j < VPL; j++) outF[(size_t)r * D + lane * VPL + j] = res[j];
    }
}

// ---------------------------------------------------------------------------
// Launch
// ---------------------------------------------------------------------------
extern "C" void kernel_launch(void* const* d_in, const int* in_sizes, int n_in,
                              void* d_out, int out_size, void* d_ws, size_t ws_size,
                              hipStream_t stream) {
    const float* sam_feat = (const float*)d_in[0];
    const float* gen_feat = (const float*)d_in[1];
    const int* src_sg = (const int*)d_in[2];
    const int* dst_sg = (const int*)d_in[3];
    const int* src_gs = (const int*)d_in[4];
    const int* dst_gs = (const int*)d_in[5];
    const float* l1W = (const float*)d_in[6];
    const float* l1b = (const float*)d_in[7];
    const float* l2W = (const float*)d_in[8];
    const float* l2b = (const float*)d_in[9];
    const float* Wsg[3] = {(const float*)d_in[10], (const float*)d_in[14], (const float*)d_in[18]};
    const float* bsg[3] = {(const float*)d_in[11], (const float*)d_in[15], (const float*)d_in[19]};
    const float* Wgs[3] = {(const float*)d_in[12], (const float*)d_in[16], (const float*)d_in[20]};
    const float* bgs[3] = {(const float*)d_in[13], (const float*)d_in[17], (const float*)d_in[21]};
    const int NE = in_sizes[2];

    // ---- workspace carve ----
    char* base = (char*)d_ws;
    size_t off = 0;
    auto alloc = [&](size_t bytes) -> char* {
        char* p = base + off;
        off = (off + bytes + 255) & ~(size_t)255;
        return p;
    };
    unsigned* cnt_ssg = (unsigned*)alloc(N_SAM * 4);
    unsigned* cnt_dsg = (unsigned*)alloc(N_GEN * 4);
    unsigned* cnt_sgs = (unsigned*)alloc(N_GEN * 4);
    unsigned* cnt_dgs = (unsigned*)alloc(N_SAM * 4);
    size_t cnt_bytes = off;  // contiguous zero region
    unsigned* row_sg = (unsigned*)alloc((N_GEN + 1) * 4);
    unsigned* row_gs = (unsigned*)alloc((N_SAM + 1) * 4);
    unsigned* cur_sg = (unsigned*)alloc(N_GEN * 4);
    unsigned* cur_gs = (unsigned*)alloc(N_SAM * 4);
    float* rs_out_sam = (float*)alloc(N_SAM * 4);
    float* rs_in_sam  = (float*)alloc(N_SAM * 4);
    float* rs_out_gen = (float*)alloc(N_GEN * 4);
    float* rs_in_gen  = (float*)alloc(N_GEN * 4);
    int* col_sg = (int*)alloc((size_t)NE * 4);
    int* col_gs = (int*)alloc((size_t)NE * 4);
    // bf16 activation buffers
    unsigned short* hs = (unsigned short*)alloc((size_t)N_SAM * 256 * 2);
    unsigned short* hg = (unsigned short*)alloc((size_t)N_GEN * 256 * 2);
    unsigned short* ps = (unsigned short*)alloc((size_t)N_SAM * 256 * 2);
    unsigned short* pg = (unsigned short*)alloc((size_t)N_GEN * 256 * 2);
    // transposed bf16 weights [N][Kp]
    const int KP1 = 2016, KP2 = 512;  // ceil32(2000), ceil32(500)
    unsigned short* BT_l1 = (unsigned short*)alloc((size_t)256 * KP1 * 2);
    unsigned short* BT_l2 = (unsigned short*)alloc((size_t)256 * KP2 * 2);
    unsigned short* BT_sg[3], *BT_gs[3];
    const int LN[3] = {256, 128, 64};   // layer output dims
    const int LK[3] = {256, 256, 128};  // layer input dims
    for (int i = 0; i < 3; i++) {
        BT_sg[i] = (unsigned short*)alloc((size_t)LN[i] * LK[i] * 2);
        BT_gs[i] = (unsigned short*)alloc((size_t)LN[i] * LK[i] * 2);
    }
    (void)ws_size;

    // ---- graph preprocessing ----
    hipMemsetAsync(base, 0, cnt_bytes, stream);
    int neb = (NE + 255) / 256;
    hist4_kernel<<<neb, 256, 0, stream>>>(src_sg, dst_sg, src_gs, dst_gs,
                                          cnt_ssg, cnt_dsg, cnt_sgs, cnt_dgs, NE);
    scan2_kernel<<<2, 1024, 0, stream>>>(cnt_dsg, row_sg, cur_sg, N_GEN,
                                         cnt_dgs, row_gs, cur_gs, N_SAM);
    degnorm_kernel<<<(N_GEN + 255) / 256, 256, 0, stream>>>(
        cnt_ssg, cnt_dsg, cnt_sgs, cnt_dgs,
        rs_out_sam, rs_in_gen, rs_out_gen, rs_in_sam);
    scatter2_kernel<<<neb, 256, 0, stream>>>(src_sg, dst_sg, src_gs, dst_gs,
                                             cur_sg, col_sg, cur_gs, col_gs, NE);

    // ---- weight transpose+convert (all 8 in one launch) ----
    WPack wp;
    wp.d[0] = {l1W,    BT_l1,    DSAM, 256, KP1};
    wp.d[1] = {l2W,    BT_l2,    DGEN, 256, KP2};
    wp.d[2] = {Wsg[0], BT_sg[0], 256, 256, 256};
    wp.d[3] = {Wgs[0], BT_gs[0], 256, 256, 256};
    wp.d[4] = {Wsg[1], BT_sg[1], 256, 128, 256};
    wp.d[5] = {Wgs[1], BT_gs[1], 256, 128, 256};
    wp.d[6] = {Wsg[2], BT_sg[2], 128, 64, 128};
    wp.d[7] = {Wgs[2], BT_gs[2], 128, 64, 128};
    transpose_weights_kernel<<<dim3(8, KP1 / 8, 8), dim3(32, 8), 0, stream>>>(wp);

    dim3 blk(256);
    const int GY_SAM = (N_SAM + 63) / 64;  // 157
    const int GY_GEN = (N_GEN + 63) / 64;  // 313

    // ---- input projections ----
    gemm_mfma<float><<<dim3(4, GY_SAM), blk, 0, stream>>>(
        sam_feat, BT_l1, nullptr, l1b, hs, N_SAM, 256, DSAM, KP1);
    gemm_mfma<float><<<dim3(4, GY_GEN), blk, 0, stream>>>(
        gen_feat, BT_l2, nullptr, l2b, hg, N_GEN, 256, DGEN, KP2);

    // ---- layer 1: 256 -> 256 ----
    gemm_mfma<unsigned short><<<dim3(4, GY_SAM), blk, 0, stream>>>(
        hs, BT_sg[0], rs_out_sam, nullptr, ps, N_SAM, 256, 256, 256);
    gemm_mfma<unsigned short><<<dim3(4, GY_GEN), blk, 0, stream>>>(
        hg, BT_gs[0], rs_out_gen, nullptr, pg, N_GEN, 256, 256, 256);
    agg_csr_kernel<4, true><<<(N_GEN + 3) / 4, blk, 0, stream>>>(
        row_sg, col_sg, ps, rs_in_gen, bsg[0], nullptr, hg, N_GEN);
    agg_csr_kernel<4, true><<<(N_SAM + 3) / 4, blk, 0, stream>>>(
        row_gs, col_gs, pg, rs_in_sam, bgs[0], nullptr, hs, N_SAM);

    // ---- layer 2: 256 -> 128 ----
    gemm_mfma<unsigned short><<<dim3(2, GY_SAM), blk, 0, stream>>>(
        hs, BT_sg[1], rs_out_sam, nullptr, ps, N_SAM, 128, 256, 256);
    gemm_mfma<unsigned short><<<dim3(2, GY_GEN), blk, 0, stream>>>(
        hg, BT_gs[1], rs_out_gen, nullptr, pg, N_GEN, 128, 256, 256);
    agg_csr_kernel<2, true><<<(N_GEN + 3) / 4, blk, 0, stream>>>(
        row_sg, col_sg, ps, rs_in_gen, bsg[1], nullptr, hg, N_GEN);
    agg_csr_kernel<2, true><<<(N_SAM + 3) / 4, blk, 0, stream>>>(
        row_gs, col_gs, pg, rs_in_sam, bgs[1], nullptr, hs, N_SAM);

    // ---- layer 3: 128 -> 64, fp32 outputs straight into d_out ----
    gemm_mfma<unsigned short><<<dim3(1, GY_SAM), blk, 0, stream>>>(
        hs, BT_sg[2], rs_out_sam, nullptr, ps, N_SAM, 64, 128, 128);
    gemm_mfma<unsigned short><<<dim3(1, GY_GEN), blk, 0, stream>>>(
        hg, BT_gs[2], rs_out_gen, nullptr, pg, N_GEN, 64, 128, 128);
    float* out_sam = (float*)d_out;
    float* out_gen = out_sam + (size_t)N_SAM * 64;
    agg_csr_kernel<1, false><<<(N_GEN + 3) / 4, blk, 0, stream>>>(
        row_sg, col_sg, ps, rs_in_gen, bsg[2], out_gen, nullptr, N_GEN);
    agg_csr_kernel<1, false><<<(N_SAM + 3) / 4, blk, 0, stream>>>(
        row_gs, col_gs, pg, rs_in_sam, bgs[2], out_sam, nullptr, N_SAM);
}

// Round 6
// 842.127 us; speedup vs baseline: 2.1060x; 1.2466x over previous
//
#include <hip/hip_runtime.h>
#include <hip/hip_bf16.h>
#include <stdint.h>

#define N_SAM 10000
#define N_GEN 20000
#define DSAM  2000
#define DGEN  500
#define NB    32      // counting-sort blocks (edge chunks)
#define NBNS  10240   // max LDS bins per slice (40 KB)

typedef __hip_bfloat16 bf16;
typedef short bf16x8 __attribute__((ext_vector_type(8)));
typedef float f32x4 __attribute__((ext_vector_type(4)));

__device__ __forceinline__ float bfbits2f(unsigned short u) {
    unsigned v = ((unsigned)u) << 16;
    return __builtin_bit_cast(float, v);
}
__device__ __forceinline__ unsigned short f2bfbits(float f) {
    bf16 h = __float2bfloat16(f);
    return __builtin_bit_cast(unsigned short, h);
}

// ---------------------------------------------------------------------------
// Counting-sort phase 1: per-(block,bin) histograms, LDS-privatized, NO global
// atomics. Blocks partition edges into NB contiguous chunks (same chunks used
// by scatter). Slices (blockIdx.y) cover (array, bin-subrange) with <=NBNS bins.
// ---------------------------------------------------------------------------
__global__ __launch_bounds__(256) void hist_count_kernel(
    const int* __restrict__ ssg, const int* __restrict__ dsg,
    const int* __restrict__ sgs, const int* __restrict__ dgs,
    unsigned* __restrict__ cs_ssg, unsigned* __restrict__ cs_dsg,
    unsigned* __restrict__ cs_sgs, unsigned* __restrict__ cs_dgs,
    int ne, int chunk) {
    __shared__ unsigned bins[NBNS];
    const int* arr; unsigned* counts; int lo, hi, nb;
    switch (blockIdx.y) {
        case 0:  arr = ssg; counts = cs_ssg; lo = 0;     hi = 10000; nb = 10000; break;
        case 1:  arr = dsg; counts = cs_dsg; lo = 0;     hi = 10240; nb = 20000; break;
        case 2:  arr = dsg; counts = cs_dsg; lo = 10240; hi = 20000; nb = 20000; break;
        case 3:  arr = sgs; counts = cs_sgs; lo = 0;     hi = 10240; nb = 20000; break;
        case 4:  arr = sgs; counts = cs_sgs; lo = 10240; hi = 20000; nb = 20000; break;
        default: arr = dgs; counts = cs_dgs; lo = 0;     hi = 10000; nb = 10000; break;
    }
    int span = hi - lo;
    for (int i = threadIdx.x; i < span; i += 256) bins[i] = 0u;
    __syncthreads();
    int blk = blockIdx.x;
    int e0 = blk * chunk;
    int e1 = e0 + chunk; if (e1 > ne) e1 = ne;
    for (int e = e0 + threadIdx.x; e < e1; e += 256) {
        int b = arr[e];
        if (b >= lo && b < hi) atomicAdd(&bins[b - lo], 1u);
    }
    __syncthreads();
    unsigned* out = counts + (size_t)blk * nb + lo;
    for (int i = threadIdx.x; i < span; i += 256) out[i] = bins[i];
}

// ---------------------------------------------------------------------------
// Reduce per-block counts -> totals; fused degree normalizers rsqrt(max(d,1)).
// ---------------------------------------------------------------------------
__global__ __launch_bounds__(256) void reduce_counts_kernel(
    const unsigned* __restrict__ cs_ssg, const unsigned* __restrict__ cs_dsg,
    const unsigned* __restrict__ cs_sgs, const unsigned* __restrict__ cs_dgs,
    unsigned* __restrict__ cnt_dsg, unsigned* __restrict__ cnt_dgs,
    float* __restrict__ rs_out_sam, float* __restrict__ rs_in_gen,
    float* __restrict__ rs_out_gen, float* __restrict__ rs_in_sam) {
    int i = blockIdx.x * 256 + threadIdx.x;
    int which = blockIdx.y;
    const unsigned* cs; int nb;
    switch (which) {
        case 0:  cs = cs_ssg; nb = 10000; break;
        case 1:  cs = cs_dsg; nb = 20000; break;
        case 2:  cs = cs_sgs; nb = 20000; break;
        default: cs = cs_dgs; nb = 10000; break;
    }
    if (i >= nb) return;
    unsigned s = 0;
    #pragma unroll 4
    for (int b = 0; b < NB; b++) s += cs[(size_t)b * nb + i];
    unsigned c = (s < 1u) ? 1u : s;
    float r = rsqrtf((float)c);
    if (which == 0)      { rs_out_sam[i] = r; }
    else if (which == 1) { cnt_dsg[i] = s; rs_in_gen[i] = r; }
    else if (which == 2) { rs_out_gen[i] = r; }
    else                 { cnt_dgs[i] = s; rs_in_sam[i] = r; }
}

// ---------------------------------------------------------------------------
// Two exclusive scans in one launch (block 0 / block 1). row[n] = total.
// ---------------------------------------------------------------------------
__global__ __launch_bounds__(1024) void scan2_kernel(
    const unsigned* __restrict__ c0, unsigned* __restrict__ r0, int nA,
    const unsigned* __restrict__ c1, unsigned* __restrict__ r1, int nB) {
    const unsigned* cnt; unsigned* row; int n;
    if (blockIdx.x == 0) { cnt = c0; row = r0; n = nA; }
    else                 { cnt = c1; row = r1; n = nB; }
    __shared__ unsigned sdata[1024];
    __shared__ unsigned carry_s;
    int t = threadIdx.x;
    if (t == 0) carry_s = 0;
    __syncthreads();
    for (int base = 0; base < n; base += 1024) {
        int i = base + t;
        unsigned v = (i < n) ? cnt[i] : 0u;
        sdata[t] = v;
        __syncthreads();
        for (int off = 1; off < 1024; off <<= 1) {
            unsigned add = (t >= off) ? sdata[t - off] : 0u;
            __syncthreads();
            sdata[t] += add;
            __syncthreads();
        }
        unsigned incl = sdata[t];
        unsigned carry = carry_s;
        if (i < n) row[i] = carry + incl - v;
        __syncthreads();
        if (t == 1023) carry_s = carry + incl;
        __syncthreads();
    }
    if (t == 0) row[n] = carry_s;
}

// ---------------------------------------------------------------------------
// Per-(block,bin) starting cursors: cur[blk][b] = row[b] + sum_{blk'<blk} cnt
// ---------------------------------------------------------------------------
__global__ __launch_bounds__(256) void cursor_kernel(
    const unsigned* __restrict__ cs_dsg, const unsigned* __restrict__ cs_dgs,
    const unsigned* __restrict__ row_sg, const unsigned* __restrict__ row_gs,
    unsigned* __restrict__ cur_sg_m, unsigned* __restrict__ cur_gs_m) {
    int i = blockIdx.x * 256 + threadIdx.x;
    const unsigned* cs; const unsigned* row; unsigned* cur; int nb;
    if (blockIdx.y == 0) { cs = cs_dsg; row = row_sg; cur = cur_sg_m; nb = 20000; }
    else                 { cs = cs_dgs; row = row_gs; cur = cur_gs_m; nb = 10000; }
    if (i >= nb) return;
    unsigned run = row[i];
    for (int b = 0; b < NB; b++) {
        cur[(size_t)b * nb + i] = run;
        run += cs[(size_t)b * nb + i];
    }
}

// ---------------------------------------------------------------------------
// Counting-sort phase 2: place edges with LDS cursors (no global atomics).
// Same chunk partition as hist. Slices split dst ranges to fit LDS.
// ---------------------------------------------------------------------------
__global__ __launch_bounds__(256) void scatter_sorted_kernel(
    const int* __restrict__ src_sg, const int* __restrict__ dst_sg,
    const int* __restrict__ src_gs, const int* __restrict__ dst_gs,
    const unsigned* __restrict__ cur_sg_m, const unsigned* __restrict__ cur_gs_m,
    int* __restrict__ col_sg, int* __restrict__ col_gs, int ne, int chunk) {
    __shared__ unsigned curs[NBNS];
    const int* src; const int* dst; const unsigned* cmat; int* col; int lo, hi, nb;
    switch (blockIdx.y) {
        case 0:  src = src_sg; dst = dst_sg; cmat = cur_sg_m; col = col_sg; lo = 0;     hi = 10240; nb = 20000; break;
        case 1:  src = src_sg; dst = dst_sg; cmat = cur_sg_m; col = col_sg; lo = 10240; hi = 20000; nb = 20000; break;
        default: src = src_gs; dst = dst_gs; cmat = cur_gs_m; col = col_gs; lo = 0;     hi = 10000; nb = 10000; break;
    }
    int span = hi - lo, blk = blockIdx.x;
    const unsigned* cin = cmat + (size_t)blk * nb + lo;
    for (int i = threadIdx.x; i < span; i += 256) curs[i] = cin[i];
    __syncthreads();
    int e0 = blk * chunk;
    int e1 = e0 + chunk; if (e1 > ne) e1 = ne;
    for (int e = e0 + threadIdx.x; e < e1; e += 256) {
        int d = dst[e];
        if (d >= lo && d < hi) {
            unsigned p = atomicAdd(&curs[d - lo], 1u);
            col[p] = src[e];
        }
    }
}

// ---------------------------------------------------------------------------
// Weight transpose+convert: W[K][N] fp32 -> WT[N][Kp] bf16, zero-pad [K,Kp)
// ---------------------------------------------------------------------------
struct WDesc { const float* src; unsigned short* dst; int K, N, Kp; };
struct WPack { WDesc d[8]; };

__global__ __launch_bounds__(256) void transpose_weights_kernel(WPack p) {
    WDesc d = p.d[blockIdx.z];
    int n  = blockIdx.x * 32 + threadIdx.x;
    int kp = blockIdx.y * 8 + threadIdx.y;
    if (n >= d.N || kp >= d.Kp) return;
    float v = (kp < d.K) ? d.src[(size_t)kp * d.N + n] : 0.0f;
    d.dst[(size_t)n * d.Kp + kp] = f2bfbits(v);
}

// ---------------------------------------------------------------------------
// MFMA bf16 GEMM: C[M][N](bf16) = A[M][K] * BT[N][Kp]^T; epilogue
// (+bias[col]) (*rs[row]). A fp32 or bf16 row-major stride K; BT bf16 [N][Kp]
// zero-padded, Kp%64==0. 256 thr = 4 waves; tile 64x64; wave 32x32 (2x2
// mfma_f32_16x16x32_bf16); BK=64; LDS rows padded to 72 shorts.
// ---------------------------------------------------------------------------
template <typename AT>
__global__ __launch_bounds__(256) void gemm_mfma(
    const AT* __restrict__ A, const unsigned short* __restrict__ BT,
    const float* __restrict__ bias, const float* __restrict__ rs,
    unsigned short* __restrict__ C, int M, int N, int K, int Kp) {
    const int BKP = 72;
    __shared__ __attribute__((aligned(16))) unsigned short As[64][BKP];
    __shared__ __attribute__((aligned(16))) unsigned short Bs[64][BKP];
    int t = threadIdx.x;
    int m0 = blockIdx.y * 64, n0 = blockIdx.x * 64;
    int wave = t >> 6, lane = t & 63;
    int wm = (wave >> 1) * 32, wn = (wave & 1) * 32;
    int q = lane >> 4, mr = lane & 15;
    int lr = t >> 2, lk = (t & 3) * 16;
    int gm = m0 + lr;

    f32x4 acc[2][2] = {};

    for (int k0 = 0; k0 < Kp; k0 += 64) {
        // ---- stage A tile (64 rows x 64 k) ----
        {
            int gk = k0 + lk;
            if (gm < M && gk + 16 <= K) {
                if constexpr (sizeof(AT) == 4) {
                    const float* ap = (const float*)A + (size_t)gm * K + gk;
                    #pragma unroll
                    for (int c = 0; c < 4; c++) {
                        float4 u = *reinterpret_cast<const float4*>(ap + c * 4);
                        As[lr][lk + c * 4 + 0] = f2bfbits(u.x);
                        As[lr][lk + c * 4 + 1] = f2bfbits(u.y);
                        As[lr][lk + c * 4 + 2] = f2bfbits(u.z);
                        As[lr][lk + c * 4 + 3] = f2bfbits(u.w);
                    }
                } else {
                    const unsigned short* ap = (const unsigned short*)A + (size_t)gm * K + gk;
                    #pragma unroll
                    for (int c = 0; c < 4; c++)
                        *reinterpret_cast<ushort4*>(&As[lr][lk + c * 4]) =
                            *reinterpret_cast<const ushort4*>(ap + c * 4);
                }
            } else {
                #pragma unroll
                for (int j = 0; j < 16; j++) {
                    float v = 0.0f;
                    int k = gk + j;
                    if (gm < M && k < K) {
                        if constexpr (sizeof(AT) == 4) v = ((const float*)A)[(size_t)gm * K + k];
                        else v = bfbits2f(((const unsigned short*)A)[(size_t)gm * K + k]);
                    }
                    As[lr][lk + j] = f2bfbits(v);
                }
            }
        }
        // ---- stage B tile (BT padded; N%64==0) ----
        {
            const unsigned short* bp = BT + (size_t)(n0 + lr) * Kp + k0 + lk;
            #pragma unroll
            for (int c = 0; c < 4; c++)
                *reinterpret_cast<ushort4*>(&Bs[lr][lk + c * 4]) =
                    *reinterpret_cast<const ushort4*>(bp + c * 4);
        }
        __syncthreads();
        // ---- compute: 2 k-steps x (2x2) mfma 16x16x32 per wave ----
        #pragma unroll
        for (int kk = 0; kk < 64; kk += 32) {
            bf16x8 af[2], bf[2];
            #pragma unroll
            for (int i = 0; i < 2; i++)
                af[i] = *reinterpret_cast<const bf16x8*>(&As[wm + i * 16 + mr][kk + q * 8]);
            #pragma unroll
            for (int j = 0; j < 2; j++)
                bf[j] = *reinterpret_cast<const bf16x8*>(&Bs[wn + j * 16 + mr][kk + q * 8]);
            #pragma unroll
            for (int i = 0; i < 2; i++)
                #pragma unroll
                for (int j = 0; j < 2; j++)
                    acc[i][j] = __builtin_amdgcn_mfma_f32_16x16x32_bf16(af[i], bf[j], acc[i][j], 0, 0, 0);
        }
        __syncthreads();
    }
    // ---- epilogue: row=(lane>>4)*4+reg, col=lane&15 per 16x16 tile ----
    #pragma unroll
    for (int i = 0; i < 2; i++) {
        #pragma unroll
        for (int r = 0; r < 4; r++) {
            int row = m0 + wm + i * 16 + q * 4 + r;
            if (row >= M) continue;
            float sc = (rs != nullptr) ? rs[row] : 1.0f;
            #pragma unroll
            for (int j = 0; j < 2; j++) {
                int col = n0 + wn + j * 16 + mr;
                float v = acc[i][j][r];
                if (bias != nullptr) v += bias[col];
                v *= sc;
                C[(size_t)row * N + col] = f2bfbits(v);
            }
        }
    }
}

// ---------------------------------------------------------------------------
// CSR aggregation over bf16 P. One wave per dst row, VPL cols/lane (D=64*VPL).
// out = leaky(rs_in[r]*sum P[col[e],:] + bias); bf16 path scales by rs_next[r]
// (pre-applied out-degree norm for the NEXT layer's GEMM).
// ---------------------------------------------------------------------------
template <int VPL>
__device__ __forceinline__ void load_bf16_row(const unsigned short* p, float* v);
template <>
__device__ __forceinline__ void load_bf16_row<4>(const unsigned short* p, float* v) {
    ushort4 u = *reinterpret_cast<const ushort4*>(p);
    v[0] = bfbits2f(u.x); v[1] = bfbits2f(u.y);
    v[2] = bfbits2f(u.z); v[3] = bfbits2f(u.w);
}
template <>
__device__ __forceinline__ void load_bf16_row<2>(const unsigned short* p, float* v) {
    ushort2 u = *reinterpret_cast<const ushort2*>(p);
    v[0] = bfbits2f(u.x); v[1] = bfbits2f(u.y);
}
template <>
__device__ __forceinline__ void load_bf16_row<1>(const unsigned short* p, float* v) {
    v[0] = bfbits2f(*p);
}

template <int VPL, bool OUTBF>
__global__ __launch_bounds__(256) void agg_csr_kernel(
    const unsigned* __restrict__ rowptr, const int* __restrict__ col,
    const unsigned short* __restrict__ P, const float* __restrict__ rs_in,
    const float* __restrict__ bias, const float* __restrict__ rs_next,
    float* __restrict__ outF, unsigned short* __restrict__ outB, int n_dst) {
    const int D = VPL * 64;
    int wave = threadIdx.x >> 6;
    int lane = threadIdx.x & 63;
    int r = blockIdx.x * 4 + wave;
    if (r >= n_dst) return;

    unsigned e0 = rowptr[r], e1 = rowptr[r + 1];
    float acc[VPL] = {};
    float acc2[VPL] = {};
    float t0[VPL], t1[VPL];
    unsigned e = e0;
    for (; e + 2 <= e1; e += 2) {
        int s0 = col[e];
        int s1 = col[e + 1];
        load_bf16_row<VPL>(P + (size_t)s0 * D + lane * VPL, t0);
        load_bf16_row<VPL>(P + (size_t)s1 * D + lane * VPL, t1);
        #pragma unroll
        for (int j = 0; j < VPL; j++) { acc[j] += t0[j]; acc2[j] += t1[j]; }
    }
    if (e < e1) {
        int s0 = col[e];
        load_bf16_row<VPL>(P + (size_t)s0 * D + lane * VPL, t0);
        #pragma unroll
        for (int j = 0; j < VPL; j++) acc[j] += t0[j];
    }
    float rsv = rs_in[r];
    float res[VPL];
    #pragma unroll
    for (int j = 0; j < VPL; j++) {
        float v = (acc[j] + acc2[j]) * rsv + bias[lane * VPL + j];
        res[j] = (v >= 0.f) ? v : 0.25f * v;
    }
    if constexpr (OUTBF) {
        float sn = rs_next[r];
        unsigned short* op = outB + (size_t)r * D + lane * VPL;
        if constexpr (VPL == 4) {
            *reinterpret_cast<ushort4*>(op) = make_ushort4(
                f2bfbits(res[0] * sn), f2bfbits(res[1] * sn),
                f2bfbits(res[2] * sn), f2bfbits(res[3] * sn));
        } else if constexpr (VPL == 2) {
            *reinterpret_cast<ushort2*>(op) = make_ushort2(
                f2bfbits(res[0] * sn), f2bfbits(res[1] * sn));
        } else {
            *op = f2bfbits(res[0] * sn);
        }
    } else {
        #pragma unroll
        for (int j = 0; j < VPL; j++) outF[(size_t)r * D + lane * VPL + j] = res[j];
    }
}

// ---------------------------------------------------------------------------
// Launch
// ---------------------------------------------------------------------------
extern "C" void kernel_launch(void* const* d_in, const int* in_sizes, int n_in,
                              void* d_out, int out_size, void* d_ws, size_t ws_size,
                              hipStream_t stream) {
    const float* sam_feat = (const float*)d_in[0];
    const float* gen_feat = (const float*)d_in[1];
    const int* src_sg = (const int*)d_in[2];
    const int* dst_sg = (const int*)d_in[3];
    const int* src_gs = (const int*)d_in[4];
    const int* dst_gs = (const int*)d_in[5];
    const float* l1W = (const float*)d_in[6];
    const float* l1b = (const float*)d_in[7];
    const float* l2W = (const float*)d_in[8];
    const float* l2b = (const float*)d_in[9];
    const float* Wsg[3] = {(const float*)d_in[10], (const float*)d_in[14], (const float*)d_in[18]};
    const float* bsg[3] = {(const float*)d_in[11], (const float*)d_in[15], (const float*)d_in[19]};
    const float* Wgs[3] = {(const float*)d_in[12], (const float*)d_in[16], (const float*)d_in[20]};
    const float* bgs[3] = {(const float*)d_in[13], (const float*)d_in[17], (const float*)d_in[21]};
    const int NE = in_sizes[2];
    const int CHUNK = (NE + NB - 1) / NB;

    // ---- workspace carve (~53 MB) ----
    char* base = (char*)d_ws;
    size_t off = 0;
    auto alloc = [&](size_t bytes) -> char* {
        char* p = base + off;
        off = (off + bytes + 255) & ~(size_t)255;
        return p;
    };
    unsigned* cs_ssg = (unsigned*)alloc((size_t)NB * N_SAM * 4);
    unsigned* cs_dsg = (unsigned*)alloc((size_t)NB * N_GEN * 4);
    unsigned* cs_sgs = (unsigned*)alloc((size_t)NB * N_GEN * 4);
    unsigned* cs_dgs = (unsigned*)alloc((size_t)NB * N_SAM * 4);
    unsigned* cnt_dsg = (unsigned*)alloc(N_GEN * 4);
    unsigned* cnt_dgs = (unsigned*)alloc(N_SAM * 4);
    unsigned* row_sg = (unsigned*)alloc((N_GEN + 1) * 4);
    unsigned* row_gs = (unsigned*)alloc((N_SAM + 1) * 4);
    unsigned* cur_sg_m = (unsigned*)alloc((size_t)NB * N_GEN * 4);
    unsigned* cur_gs_m = (unsigned*)alloc((size_t)NB * N_SAM * 4);
    float* rs_out_sam = (float*)alloc(N_SAM * 4);
    float* rs_in_sam  = (float*)alloc(N_SAM * 4);
    float* rs_out_gen = (float*)alloc(N_GEN * 4);
    float* rs_in_gen  = (float*)alloc(N_GEN * 4);
    int* col_sg = (int*)alloc((size_t)NE * 4);
    int* col_gs = (int*)alloc((size_t)NE * 4);
    unsigned short* hs = (unsigned short*)alloc((size_t)N_SAM * 256 * 2);
    unsigned short* hg = (unsigned short*)alloc((size_t)N_GEN * 256 * 2);
    unsigned short* ps = (unsigned short*)alloc((size_t)N_SAM * 256 * 2);
    unsigned short* pg = (unsigned short*)alloc((size_t)N_GEN * 256 * 2);
    const int KP1 = 2048, KP2 = 512;
    unsigned short* BT_l1 = (unsigned short*)alloc((size_t)256 * KP1 * 2);
    unsigned short* BT_l2 = (unsigned short*)alloc((size_t)256 * KP2 * 2);
    unsigned short* BT_sg[3], *BT_gs[3];
    const int LN[3] = {256, 128, 64};
    const int LK[3] = {256, 256, 128};
    for (int i = 0; i < 3; i++) {
        BT_sg[i] = (unsigned short*)alloc((size_t)LN[i] * LK[i] * 2);
        BT_gs[i] = (unsigned short*)alloc((size_t)LN[i] * LK[i] * 2);
    }
    (void)ws_size;

    // ---- graph preprocessing: atomic-free counting sort ----
    hist_count_kernel<<<dim3(NB, 6), 256, 0, stream>>>(
        src_sg, dst_sg, src_gs, dst_gs, cs_ssg, cs_dsg, cs_sgs, cs_dgs, NE, CHUNK);
    reduce_counts_kernel<<<dim3((N_GEN + 255) / 256, 4), 256, 0, stream>>>(
        cs_ssg, cs_dsg, cs_sgs, cs_dgs, cnt_dsg, cnt_dgs,
        rs_out_sam, rs_in_gen, rs_out_gen, rs_in_sam);
    scan2_kernel<<<2, 1024, 0, stream>>>(cnt_dsg, row_sg, N_GEN, cnt_dgs, row_gs, N_SAM);
    cursor_kernel<<<dim3((N_GEN + 255) / 256, 2), 256, 0, stream>>>(
        cs_dsg, cs_dgs, row_sg, row_gs, cur_sg_m, cur_gs_m);
    scatter_sorted_kernel<<<dim3(NB, 3), 256, 0, stream>>>(
        src_sg, dst_sg, src_gs, dst_gs, cur_sg_m, cur_gs_m, col_sg, col_gs, NE, CHUNK);

    // ---- weight transpose+convert ----
    WPack wp;
    wp.d[0] = {l1W,    BT_l1,    DSAM, 256, KP1};
    wp.d[1] = {l2W,    BT_l2,    DGEN, 256, KP2};
    wp.d[2] = {Wsg[0], BT_sg[0], 256, 256, 256};
    wp.d[3] = {Wgs[0], BT_gs[0], 256, 256, 256};
    wp.d[4] = {Wsg[1], BT_sg[1], 256, 128, 256};
    wp.d[5] = {Wgs[1], BT_gs[1], 256, 128, 256};
    wp.d[6] = {Wsg[2], BT_sg[2], 128, 64, 128};
    wp.d[7] = {Wgs[2], BT_gs[2], 128, 64, 128};
    transpose_weights_kernel<<<dim3(8, KP1 / 8, 8), dim3(32, 8), 0, stream>>>(wp);

    dim3 blk(256);
    const int GY_SAM = (N_SAM + 63) / 64;  // 157
    const int GY_GEN = (N_GEN + 63) / 64;  // 313

    // ---- input projections (epilogue: (acc+bias)*rs_out -> pre-scaled H) ----
    gemm_mfma<float><<<dim3(4, GY_SAM), blk, 0, stream>>>(
        sam_feat, BT_l1, l1b, rs_out_sam, hs, N_SAM, 256, DSAM, KP1);
    gemm_mfma<float><<<dim3(4, GY_GEN), blk, 0, stream>>>(
        gen_feat, BT_l2, l2b, rs_out_gen, hg, N_GEN, 256, DGEN, KP2);

    // ---- layer 1: 256 -> 256 ----
    gemm_mfma<unsigned short><<<dim3(4, GY_SAM), blk, 0, stream>>>(
        hs, BT_sg[0], nullptr, nullptr, ps, N_SAM, 256, 256, 256);
    gemm_mfma<unsigned short><<<dim3(4, GY_GEN), blk, 0, stream>>>(
        hg, BT_gs[0], nullptr, nullptr, pg, N_GEN, 256, 256, 256);
    agg_csr_kernel<4, true><<<(N_GEN + 3) / 4, blk, 0, stream>>>(
        row_sg, col_sg, ps, rs_in_gen, bsg[0], rs_out_gen, nullptr, hg, N_GEN);
    agg_csr_kernel<4, true><<<(N_SAM + 3) / 4, blk, 0, stream>>>(
        row_gs, col_gs, pg, rs_in_sam, bgs[0], rs_out_sam, nullptr, hs, N_SAM);

    // ---- layer 2: 256 -> 128 ----
    gemm_mfma<unsigned short><<<dim3(2, GY_SAM), blk, 0, stream>>>(
        hs, BT_sg[1], nullptr, nullptr, ps, N_SAM, 128, 256, 256);
    gemm_mfma<unsigned short><<<dim3(2, GY_GEN), blk, 0, stream>>>(
        hg, BT_gs[1], nullptr, nullptr, pg, N_GEN, 128, 256, 256);
    agg_csr_kernel<2, true><<<(N_GEN + 3) / 4, blk, 0, stream>>>(
        row_sg, col_sg, ps, rs_in_gen, bsg[1], rs_out_gen, nullptr, hg, N_GEN);
    agg_csr_kernel<2, true><<<(N_SAM + 3) / 4, blk, 0, stream>>>(
        row_gs, col_gs, pg, rs_in_sam, bgs[1], rs_out_sam, nullptr, hs, N_SAM);

    // ---- layer 3: 128 -> 64, fp32 outputs straight into d_out ----
    gemm_mfma<unsigned short><<<dim3(1, GY_SAM), blk, 0, stream>>>(
        hs, BT_sg[2], nullptr, nullptr, ps, N_SAM, 64, 128, 128);
    gemm_mfma<unsigned short><<<dim3(1, GY_GEN), blk, 0, stream>>>(
        hg, BT_gs[2], nullptr, nullptr, pg, N_GEN, 64, 128, 128);
    float* out_sam = (float*)d_out;
    float* out_gen = out_sam + (size_t)N_SAM * 64;
    agg_csr_kernel<1, false><<<(N_GEN + 3) / 4, blk, 0, stream>>>(
        row_sg, col_sg, ps, rs_in_gen, bsg[2], nullptr, out_gen, nullptr, N_GEN);
    agg_csr_kernel<1, false><<<(N_SAM + 3) / 4, blk, 0, stream>>>(
        row_gs, col_gs, pg, rs_in_sam, bgs[2], nullptr, out_sam, nullptr, N_SAM);
}

// Round 7
// 689.030 us; speedup vs baseline: 2.5740x; 1.2222x over previous
//
#include <hip/hip_runtime.h>
#include <hip/hip_bf16.h>
#include <stdint.h>

#define N_SAM 10000
#define N_GEN 20000
#define DSAM  2000
#define DGEN  500
#define NB    32      // counting-sort blocks (edge chunks)
#define NBNS  10240   // max LDS bins per slice (40 KB)

typedef __hip_bfloat16 bf16;
typedef short bf16x8 __attribute__((ext_vector_type(8)));
typedef float f32x4 __attribute__((ext_vector_type(4)));

__device__ __forceinline__ float bfbits2f(unsigned short u) {
    unsigned v = ((unsigned)u) << 16;
    return __builtin_bit_cast(float, v);
}
__device__ __forceinline__ unsigned short f2bfbits(float f) {
    bf16 h = __float2bfloat16(f);
    return __builtin_bit_cast(unsigned short, h);
}
__device__ __forceinline__ unsigned packbf2(float lo, float hi) {
    return ((unsigned)f2bfbits(lo)) | (((unsigned)f2bfbits(hi)) << 16);
}
// accumulate 8 bf16 (16 B) into a[0..7]
__device__ __forceinline__ void acc16(const unsigned short* p, float* a) {
    uint4 u = *reinterpret_cast<const uint4*>(p);
    a[0] += __builtin_bit_cast(float, u.x << 16);
    a[1] += __builtin_bit_cast(float, u.x & 0xffff0000u);
    a[2] += __builtin_bit_cast(float, u.y << 16);
    a[3] += __builtin_bit_cast(float, u.y & 0xffff0000u);
    a[4] += __builtin_bit_cast(float, u.z << 16);
    a[5] += __builtin_bit_cast(float, u.z & 0xffff0000u);
    a[6] += __builtin_bit_cast(float, u.w << 16);
    a[7] += __builtin_bit_cast(float, u.w & 0xffff0000u);
}

// ---------------------------------------------------------------------------
// Counting-sort phase 1: per-(block,bin) histograms, LDS-privatized.
// ---------------------------------------------------------------------------
__global__ __launch_bounds__(256) void hist_count_kernel(
    const int* __restrict__ ssg, const int* __restrict__ dsg,
    const int* __restrict__ sgs, const int* __restrict__ dgs,
    unsigned* __restrict__ cs_ssg, unsigned* __restrict__ cs_dsg,
    unsigned* __restrict__ cs_sgs, unsigned* __restrict__ cs_dgs,
    int ne, int chunk) {
    __shared__ unsigned bins[NBNS];
    const int* arr; unsigned* counts; int lo, hi, nb;
    switch (blockIdx.y) {
        case 0:  arr = ssg; counts = cs_ssg; lo = 0;     hi = 10000; nb = 10000; break;
        case 1:  arr = dsg; counts = cs_dsg; lo = 0;     hi = 10240; nb = 20000; break;
        case 2:  arr = dsg; counts = cs_dsg; lo = 10240; hi = 20000; nb = 20000; break;
        case 3:  arr = sgs; counts = cs_sgs; lo = 0;     hi = 10240; nb = 20000; break;
        case 4:  arr = sgs; counts = cs_sgs; lo = 10240; hi = 20000; nb = 20000; break;
        default: arr = dgs; counts = cs_dgs; lo = 0;     hi = 10000; nb = 10000; break;
    }
    int span = hi - lo;
    for (int i = threadIdx.x; i < span; i += 256) bins[i] = 0u;
    __syncthreads();
    int blk = blockIdx.x;
    int e0 = blk * chunk;
    int e1 = e0 + chunk; if (e1 > ne) e1 = ne;
    for (int e = e0 + threadIdx.x; e < e1; e += 256) {
        int b = arr[e];
        if (b >= lo && b < hi) atomicAdd(&bins[b - lo], 1u);
    }
    __syncthreads();
    unsigned* out = counts + (size_t)blk * nb + lo;
    for (int i = threadIdx.x; i < span; i += 256) out[i] = bins[i];
}

// ---------------------------------------------------------------------------
// Reduce per-block counts -> totals; fused degree normalizers rsqrt(max(d,1)).
// ---------------------------------------------------------------------------
__global__ __launch_bounds__(256) void reduce_counts_kernel(
    const unsigned* __restrict__ cs_ssg, const unsigned* __restrict__ cs_dsg,
    const unsigned* __restrict__ cs_sgs, const unsigned* __restrict__ cs_dgs,
    unsigned* __restrict__ cnt_dsg, unsigned* __restrict__ cnt_dgs,
    float* __restrict__ rs_out_sam, float* __restrict__ rs_in_gen,
    float* __restrict__ rs_out_gen, float* __restrict__ rs_in_sam) {
    int i = blockIdx.x * 256 + threadIdx.x;
    int which = blockIdx.y;
    const unsigned* cs; int nb;
    switch (which) {
        case 0:  cs = cs_ssg; nb = 10000; break;
        case 1:  cs = cs_dsg; nb = 20000; break;
        case 2:  cs = cs_sgs; nb = 20000; break;
        default: cs = cs_dgs; nb = 10000; break;
    }
    if (i >= nb) return;
    unsigned s = 0;
    #pragma unroll 4
    for (int b = 0; b < NB; b++) s += cs[(size_t)b * nb + i];
    unsigned c = (s < 1u) ? 1u : s;
    float r = rsqrtf((float)c);
    if (which == 0)      { rs_out_sam[i] = r; }
    else if (which == 1) { cnt_dsg[i] = s; rs_in_gen[i] = r; }
    else if (which == 2) { rs_out_gen[i] = r; }
    else                 { cnt_dgs[i] = s; rs_in_sam[i] = r; }
}

// ---------------------------------------------------------------------------
// Two exclusive scans in one launch (block 0 / block 1). row[n] = total.
// ---------------------------------------------------------------------------
__global__ __launch_bounds__(1024) void scan2_kernel(
    const unsigned* __restrict__ c0, unsigned* __restrict__ r0, int nA,
    const unsigned* __restrict__ c1, unsigned* __restrict__ r1, int nB) {
    const unsigned* cnt; unsigned* row; int n;
    if (blockIdx.x == 0) { cnt = c0; row = r0; n = nA; }
    else                 { cnt = c1; row = r1; n = nB; }
    __shared__ unsigned sdata[1024];
    __shared__ unsigned carry_s;
    int t = threadIdx.x;
    if (t == 0) carry_s = 0;
    __syncthreads();
    for (int base = 0; base < n; base += 1024) {
        int i = base + t;
        unsigned v = (i < n) ? cnt[i] : 0u;
        sdata[t] = v;
        __syncthreads();
        for (int off = 1; off < 1024; off <<= 1) {
            unsigned add = (t >= off) ? sdata[t - off] : 0u;
            __syncthreads();
            sdata[t] += add;
            __syncthreads();
        }
        unsigned incl = sdata[t];
        unsigned carry = carry_s;
        if (i < n) row[i] = carry + incl - v;
        __syncthreads();
        if (t == 1023) carry_s = carry + incl;
        __syncthreads();
    }
    if (t == 0) row[n] = carry_s;
}

// ---------------------------------------------------------------------------
// Per-(block,bin) starting cursors
// ---------------------------------------------------------------------------
__global__ __launch_bounds__(256) void cursor_kernel(
    const unsigned* __restrict__ cs_dsg, const unsigned* __restrict__ cs_dgs,
    const unsigned* __restrict__ row_sg, const unsigned* __restrict__ row_gs,
    unsigned* __restrict__ cur_sg_m, unsigned* __restrict__ cur_gs_m) {
    int i = blockIdx.x * 256 + threadIdx.x;
    const unsigned* cs; const unsigned* row; unsigned* cur; int nb;
    if (blockIdx.y == 0) { cs = cs_dsg; row = row_sg; cur = cur_sg_m; nb = 20000; }
    else                 { cs = cs_dgs; row = row_gs; cur = cur_gs_m; nb = 10000; }
    if (i >= nb) return;
    unsigned run = row[i];
    for (int b = 0; b < NB; b++) {
        cur[(size_t)b * nb + i] = run;
        run += cs[(size_t)b * nb + i];
    }
}

// ---------------------------------------------------------------------------
// Counting-sort phase 2: place edges with LDS cursors (no global atomics).
// ---------------------------------------------------------------------------
__global__ __launch_bounds__(256) void scatter_sorted_kernel(
    const int* __restrict__ src_sg, const int* __restrict__ dst_sg,
    const int* __restrict__ src_gs, const int* __restrict__ dst_gs,
    const unsigned* __restrict__ cur_sg_m, const unsigned* __restrict__ cur_gs_m,
    int* __restrict__ col_sg, int* __restrict__ col_gs, int ne, int chunk) {
    __shared__ unsigned curs[NBNS];
    const int* src; const int* dst; const unsigned* cmat; int* col; int lo, hi, nb;
    switch (blockIdx.y) {
        case 0:  src = src_sg; dst = dst_sg; cmat = cur_sg_m; col = col_sg; lo = 0;     hi = 10240; nb = 20000; break;
        case 1:  src = src_sg; dst = dst_sg; cmat = cur_sg_m; col = col_sg; lo = 10240; hi = 20000; nb = 20000; break;
        default: src = src_gs; dst = dst_gs; cmat = cur_gs_m; col = col_gs; lo = 0;     hi = 10000; nb = 10000; break;
    }
    int span = hi - lo, blk = blockIdx.x;
    const unsigned* cin = cmat + (size_t)blk * nb + lo;
    for (int i = threadIdx.x; i < span; i += 256) curs[i] = cin[i];
    __syncthreads();
    int e0 = blk * chunk;
    int e1 = e0 + chunk; if (e1 > ne) e1 = ne;
    for (int e = e0 + threadIdx.x; e < e1; e += 256) {
        int d = dst[e];
        if (d >= lo && d < hi) {
            unsigned p = atomicAdd(&curs[d - lo], 1u);
            col[p] = src[e];
        }
    }
}

// ---------------------------------------------------------------------------
// Weight transpose+convert: W[K][N] fp32 -> WT[N][Kp] bf16, zero-pad [K,Kp)
// ---------------------------------------------------------------------------
struct WDesc { const float* src; unsigned short* dst; int K, N, Kp; };
struct WPack { WDesc d[8]; };

__global__ __launch_bounds__(256) void transpose_weights_kernel(WPack p) {
    WDesc d = p.d[blockIdx.z];
    int n  = blockIdx.x * 32 + threadIdx.x;
    int kp = blockIdx.y * 8 + threadIdx.y;
    if (n >= d.N || kp >= d.Kp) return;
    float v = (kp < d.K) ? d.src[(size_t)kp * d.N + n] : 0.0f;
    d.dst[(size_t)n * d.Kp + kp] = f2bfbits(v);
}

// ---------------------------------------------------------------------------
// MFMA bf16 GEMM: C[M][N](bf16) = A[M][K] * BT[N][Kp]^T; epilogue
// (+bias[col]) (*rs[row]). Tile 64x64, 4 waves, BK=64, LDS pad 72.
// ---------------------------------------------------------------------------
template <typename AT>
__global__ __launch_bounds__(256) void gemm_mfma(
    const AT* __restrict__ A, const unsigned short* __restrict__ BT,
    const float* __restrict__ bias, const float* __restrict__ rs,
    unsigned short* __restrict__ C, int M, int N, int K, int Kp) {
    const int BKP = 72;
    __shared__ __attribute__((aligned(16))) unsigned short As[64][BKP];
    __shared__ __attribute__((aligned(16))) unsigned short Bs[64][BKP];
    int t = threadIdx.x;
    int m0 = blockIdx.y * 64, n0 = blockIdx.x * 64;
    int wave = t >> 6, lane = t & 63;
    int wm = (wave >> 1) * 32, wn = (wave & 1) * 32;
    int q = lane >> 4, mr = lane & 15;
    int lr = t >> 2, lk = (t & 3) * 16;
    int gm = m0 + lr;

    f32x4 acc[2][2] = {};

    for (int k0 = 0; k0 < Kp; k0 += 64) {
        {
            int gk = k0 + lk;
            if (gm < M && gk + 16 <= K) {
                if constexpr (sizeof(AT) == 4) {
                    const float* ap = (const float*)A + (size_t)gm * K + gk;
                    #pragma unroll
                    for (int c = 0; c < 4; c++) {
                        float4 u = *reinterpret_cast<const float4*>(ap + c * 4);
                        As[lr][lk + c * 4 + 0] = f2bfbits(u.x);
                        As[lr][lk + c * 4 + 1] = f2bfbits(u.y);
                        As[lr][lk + c * 4 + 2] = f2bfbits(u.z);
                        As[lr][lk + c * 4 + 3] = f2bfbits(u.w);
                    }
                } else {
                    const unsigned short* ap = (const unsigned short*)A + (size_t)gm * K + gk;
                    #pragma unroll
                    for (int c = 0; c < 4; c++)
                        *reinterpret_cast<ushort4*>(&As[lr][lk + c * 4]) =
                            *reinterpret_cast<const ushort4*>(ap + c * 4);
                }
            } else {
                #pragma unroll
                for (int j = 0; j < 16; j++) {
                    float v = 0.0f;
                    int k = gk + j;
                    if (gm < M && k < K) {
                        if constexpr (sizeof(AT) == 4) v = ((const float*)A)[(size_t)gm * K + k];
                        else v = bfbits2f(((const unsigned short*)A)[(size_t)gm * K + k]);
                    }
                    As[lr][lk + j] = f2bfbits(v);
                }
            }
        }
        {
            const unsigned short* bp = BT + (size_t)(n0 + lr) * Kp + k0 + lk;
            #pragma unroll
            for (int c = 0; c < 4; c++)
                *reinterpret_cast<ushort4*>(&Bs[lr][lk + c * 4]) =
                    *reinterpret_cast<const ushort4*>(bp + c * 4);
        }
        __syncthreads();
        #pragma unroll
        for (int kk = 0; kk < 64; kk += 32) {
            bf16x8 af[2], bf[2];
            #pragma unroll
            for (int i = 0; i < 2; i++)
                af[i] = *reinterpret_cast<const bf16x8*>(&As[wm + i * 16 + mr][kk + q * 8]);
            #pragma unroll
            for (int j = 0; j < 2; j++)
                bf[j] = *reinterpret_cast<const bf16x8*>(&Bs[wn + j * 16 + mr][kk + q * 8]);
            #pragma unroll
            for (int i = 0; i < 2; i++)
                #pragma unroll
                for (int j = 0; j < 2; j++)
                    acc[i][j] = __builtin_amdgcn_mfma_f32_16x16x32_bf16(af[i], bf[j], acc[i][j], 0, 0, 0);
        }
        __syncthreads();
    }
    #pragma unroll
    for (int i = 0; i < 2; i++) {
        #pragma unroll
        for (int r = 0; r < 4; r++) {
            int row = m0 + wm + i * 16 + q * 4 + r;
            if (row >= M) continue;
            float sc = (rs != nullptr) ? rs[row] : 1.0f;
            #pragma unroll
            for (int j = 0; j < 2; j++) {
                int col = n0 + wn + j * 16 + mr;
                float v = acc[i][j][r];
                if (bias != nullptr) v += bias[col];
                v *= sc;
                C[(size_t)row * N + col] = f2bfbits(v);
            }
        }
    }
}

// ---------------------------------------------------------------------------
// CSR aggregation over bf16 P, MLP-optimized. One wave per dst row.
// Lanes split into R = 8/VPL edge-slots x LPR = 8*VPL row-chunk lanes
// (16 B = 8 bf16 cols per lane). Two accumulator sets (2R edges in flight).
// Cross-slot fold via shfl_down; sub==0 lanes write.
// out = leaky(rs_in[r]*sum + bias); OUTBF also scales by rs_next[r].
// ---------------------------------------------------------------------------
template <int VPL, bool OUTBF>
__global__ __launch_bounds__(256) void agg_csr_kernel(
    const unsigned* __restrict__ rowptr, const int* __restrict__ col,
    const unsigned short* __restrict__ P, const float* __restrict__ rs_in,
    const float* __restrict__ bias, const float* __restrict__ rs_next,
    float* __restrict__ outF, unsigned short* __restrict__ outB, int n_dst) {
    const int D = VPL * 64;
    const int LPR = VPL * 8;   // lanes per row (16 B each)
    const int R = 8 / VPL;     // edge slots per pass
    int wave = threadIdx.x >> 6;
    int lane = threadIdx.x & 63;
    int sub = lane / LPR;
    int li  = lane % LPR;
    int r = blockIdx.x * 4 + wave;
    if (r >= n_dst) return;

    unsigned e0 = rowptr[r], e1 = rowptr[r + 1];
    float accA[8] = {}, accB[8] = {};
    unsigned e = e0;
    for (; e + 2 * R <= e1; e += 2 * R) {
        int sA = col[e + sub];
        int sB = col[e + R + sub];
        const unsigned short* pA = P + (size_t)sA * D + li * 8;
        const unsigned short* pB = P + (size_t)sB * D + li * 8;
        acc16(pA, accA);
        acc16(pB, accB);
    }
    for (; e < e1; e += R) {
        unsigned idx = e + sub;
        if (idx < e1) {
            int s = col[idx];
            acc16(P + (size_t)s * D + li * 8, accA);
        }
    }
    #pragma unroll
    for (int j = 0; j < 8; j++) accA[j] += accB[j];
    #pragma unroll
    for (int off = 32; off >= LPR; off >>= 1) {
        #pragma unroll
        for (int j = 0; j < 8; j++) accA[j] += __shfl_down(accA[j], off);
    }
    if (sub == 0) {
        float rsv = rs_in[r];
        float res[8];
        #pragma unroll
        for (int j = 0; j < 8; j++) {
            float v = accA[j] * rsv + bias[li * 8 + j];
            res[j] = (v >= 0.f) ? v : 0.25f * v;
        }
        if constexpr (OUTBF) {
            float sn = rs_next[r];
            uint4 o;
            o.x = packbf2(res[0] * sn, res[1] * sn);
            o.y = packbf2(res[2] * sn, res[3] * sn);
            o.z = packbf2(res[4] * sn, res[5] * sn);
            o.w = packbf2(res[6] * sn, res[7] * sn);
            *reinterpret_cast<uint4*>(outB + (size_t)r * D + li * 8) = o;
        } else {
            float* op = outF + (size_t)r * D + li * 8;
            *reinterpret_cast<float4*>(op)     = make_float4(res[0], res[1], res[2], res[3]);
            *reinterpret_cast<float4*>(op + 4) = make_float4(res[4], res[5], res[6], res[7]);
        }
    }
}

// ---------------------------------------------------------------------------
// Launch
// ---------------------------------------------------------------------------
extern "C" void kernel_launch(void* const* d_in, const int* in_sizes, int n_in,
                              void* d_out, int out_size, void* d_ws, size_t ws_size,
                              hipStream_t stream) {
    const float* sam_feat = (const float*)d_in[0];
    const float* gen_feat = (const float*)d_in[1];
    const int* src_sg = (const int*)d_in[2];
    const int* dst_sg = (const int*)d_in[3];
    const int* src_gs = (const int*)d_in[4];
    const int* dst_gs = (const int*)d_in[5];
    const float* l1W = (const float*)d_in[6];
    const float* l1b = (const float*)d_in[7];
    const float* l2W = (const float*)d_in[8];
    const float* l2b = (const float*)d_in[9];
    const float* Wsg[3] = {(const float*)d_in[10], (const float*)d_in[14], (const float*)d_in[18]};
    const float* bsg[3] = {(const float*)d_in[11], (const float*)d_in[15], (const float*)d_in[19]};
    const float* Wgs[3] = {(const float*)d_in[12], (const float*)d_in[16], (const float*)d_in[20]};
    const float* bgs[3] = {(const float*)d_in[13], (const float*)d_in[17], (const float*)d_in[21]};
    const int NE = in_sizes[2];
    const int CHUNK = (NE + NB - 1) / NB;

    // ---- workspace carve ----
    char* base = (char*)d_ws;
    size_t off = 0;
    auto alloc = [&](size_t bytes) -> char* {
        char* p = base + off;
        off = (off + bytes + 255) & ~(size_t)255;
        return p;
    };
    unsigned* cs_ssg = (unsigned*)alloc((size_t)NB * N_SAM * 4);
    unsigned* cs_dsg = (unsigned*)alloc((size_t)NB * N_GEN * 4);
    unsigned* cs_sgs = (unsigned*)alloc((size_t)NB * N_GEN * 4);
    unsigned* cs_dgs = (unsigned*)alloc((size_t)NB * N_SAM * 4);
    unsigned* cnt_dsg = (unsigned*)alloc(N_GEN * 4);
    unsigned* cnt_dgs = (unsigned*)alloc(N_SAM * 4);
    unsigned* row_sg = (unsigned*)alloc((N_GEN + 1) * 4);
    unsigned* row_gs = (unsigned*)alloc((N_SAM + 1) * 4);
    unsigned* cur_sg_m = (unsigned*)alloc((size_t)NB * N_GEN * 4);
    unsigned* cur_gs_m = (unsigned*)alloc((size_t)NB * N_SAM * 4);
    float* rs_out_sam = (float*)alloc(N_SAM * 4);
    float* rs_in_sam  = (float*)alloc(N_SAM * 4);
    float* rs_out_gen = (float*)alloc(N_GEN * 4);
    float* rs_in_gen  = (float*)alloc(N_GEN * 4);
    int* col_sg = (int*)alloc((size_t)NE * 4);
    int* col_gs = (int*)alloc((size_t)NE * 4);
    unsigned short* hs = (unsigned short*)alloc((size_t)N_SAM * 256 * 2);
    unsigned short* hg = (unsigned short*)alloc((size_t)N_GEN * 256 * 2);
    unsigned short* ps = (unsigned short*)alloc((size_t)N_SAM * 256 * 2);
    unsigned short* pg = (unsigned short*)alloc((size_t)N_GEN * 256 * 2);
    const int KP1 = 2048, KP2 = 512;
    unsigned short* BT_l1 = (unsigned short*)alloc((size_t)256 * KP1 * 2);
    unsigned short* BT_l2 = (unsigned short*)alloc((size_t)256 * KP2 * 2);
    unsigned short* BT_sg[3], *BT_gs[3];
    const int LN[3] = {256, 128, 64};
    const int LK[3] = {256, 256, 128};
    for (int i = 0; i < 3; i++) {
        BT_sg[i] = (unsigned short*)alloc((size_t)LN[i] * LK[i] * 2);
        BT_gs[i] = (unsigned short*)alloc((size_t)LN[i] * LK[i] * 2);
    }
    (void)ws_size;

    // ---- graph preprocessing: atomic-free counting sort ----
    hist_count_kernel<<<dim3(NB, 6), 256, 0, stream>>>(
        src_sg, dst_sg, src_gs, dst_gs, cs_ssg, cs_dsg, cs_sgs, cs_dgs, NE, CHUNK);
    reduce_counts_kernel<<<dim3((N_GEN + 255) / 256, 4), 256, 0, stream>>>(
        cs_ssg, cs_dsg, cs_sgs, cs_dgs, cnt_dsg, cnt_dgs,
        rs_out_sam, rs_in_gen, rs_out_gen, rs_in_sam);
    scan2_kernel<<<2, 1024, 0, stream>>>(cnt_dsg, row_sg, N_GEN, cnt_dgs, row_gs, N_SAM);
    cursor_kernel<<<dim3((N_GEN + 255) / 256, 2), 256, 0, stream>>>(
        cs_dsg, cs_dgs, row_sg, row_gs, cur_sg_m, cur_gs_m);
    scatter_sorted_kernel<<<dim3(NB, 3), 256, 0, stream>>>(
        src_sg, dst_sg, src_gs, dst_gs, cur_sg_m, cur_gs_m, col_sg, col_gs, NE, CHUNK);

    // ---- weight transpose+convert ----
    WPack wp;
    wp.d[0] = {l1W,    BT_l1,    DSAM, 256, KP1};
    wp.d[1] = {l2W,    BT_l2,    DGEN, 256, KP2};
    wp.d[2] = {Wsg[0], BT_sg[0], 256, 256, 256};
    wp.d[3] = {Wgs[0], BT_gs[0], 256, 256, 256};
    wp.d[4] = {Wsg[1], BT_sg[1], 256, 128, 256};
    wp.d[5] = {Wgs[1], BT_gs[1], 256, 128, 256};
    wp.d[6] = {Wsg[2], BT_sg[2], 128, 64, 128};
    wp.d[7] = {Wgs[2], BT_gs[2], 128, 64, 128};
    transpose_weights_kernel<<<dim3(8, KP1 / 8, 8), dim3(32, 8), 0, stream>>>(wp);

    dim3 blk(256);
    const int GY_SAM = (N_SAM + 63) / 64;  // 157
    const int GY_GEN = (N_GEN + 63) / 64;  // 313

    // ---- input projections (epilogue: (acc+bias)*rs_out -> pre-scaled H) ----
    gemm_mfma<float><<<dim3(4, GY_SAM), blk, 0, stream>>>(
        sam_feat, BT_l1, l1b, rs_out_sam, hs, N_SAM, 256, DSAM, KP1);
    gemm_mfma<float><<<dim3(4, GY_GEN), blk, 0, stream>>>(
        gen_feat, BT_l2, l2b, rs_out_gen, hg, N_GEN, 256, DGEN, KP2);

    // ---- layer 1: 256 -> 256 ----
    gemm_mfma<unsigned short><<<dim3(4, GY_SAM), blk, 0, stream>>>(
        hs, BT_sg[0], nullptr, nullptr, ps, N_SAM, 256, 256, 256);
    gemm_mfma<unsigned short><<<dim3(4, GY_GEN), blk, 0, stream>>>(
        hg, BT_gs[0], nullptr, nullptr, pg, N_GEN, 256, 256, 256);
    agg_csr_kernel<4, true><<<(N_GEN + 3) / 4, blk, 0, stream>>>(
        row_sg, col_sg, ps, rs_in_gen, bsg[0], rs_out_gen, nullptr, hg, N_GEN);
    agg_csr_kernel<4, true><<<(N_SAM + 3) / 4, blk, 0, stream>>>(
        row_gs, col_gs, pg, rs_in_sam, bgs[0], rs_out_sam, nullptr, hs, N_SAM);

    // ---- layer 2: 256 -> 128 ----
    gemm_mfma<unsigned short><<<dim3(2, GY_SAM), blk, 0, stream>>>(
        hs, BT_sg[1], nullptr, nullptr, ps, N_SAM, 128, 256, 256);
    gemm_mfma<unsigned short><<<dim3(2, GY_GEN), blk, 0, stream>>>(
        hg, BT_gs[1], nullptr, nullptr, pg, N_GEN, 128, 256, 256);
    agg_csr_kernel<2, true><<<(N_GEN + 3) / 4, blk, 0, stream>>>(
        row_sg, col_sg, ps, rs_in_gen, bsg[1], rs_out_gen, nullptr, hg, N_GEN);
    agg_csr_kernel<2, true><<<(N_SAM + 3) / 4, blk, 0, stream>>>(
        row_gs, col_gs, pg, rs_in_sam, bgs[1], rs_out_sam, nullptr, hs, N_SAM);

    // ---- layer 3: 128 -> 64, fp32 outputs straight into d_out ----
    gemm_mfma<unsigned short><<<dim3(1, GY_SAM), blk, 0, stream>>>(
        hs, BT_sg[2], nullptr, nullptr, ps, N_SAM, 64, 128, 128);
    gemm_mfma<unsigned short><<<dim3(1, GY_GEN), blk, 0, stream>>>(
        hg, BT_gs[2], nullptr, nullptr, pg, N_GEN, 64, 128, 128);
    float* out_sam = (float*)d_out;
    float* out_gen = out_sam + (size_t)N_SAM * 64;
    agg_csr_kernel<1, false><<<(N_GEN + 3) / 4, blk, 0, stream>>>(
        row_sg, col_sg, ps, rs_in_gen, bsg[2], nullptr, out_gen, nullptr, N_GEN);
    agg_csr_kernel<1, false><<<(N_SAM + 3) / 4, blk, 0, stream>>>(
        row_gs, col_gs, pg, rs_in_sam, bgs[2], nullptr, out_sam, nullptr, N_SAM);
}